// Round 11
// baseline (362.494 us; speedup 1.0000x reference)
//
#include <hip/hip_runtime.h>

#define NA   16384
#define NE   524288
#define NM   256
#define FF   4800
#define FR   2496   // folded K: 3 * 832
#define FL   832
#define NPAIR 820
#define HH   512
#define NMX  10
#define NSPH 9

typedef __bf16 bf16x8 __attribute__((ext_vector_type(8)));
typedef float  f32x4  __attribute__((ext_vector_type(4)));
typedef unsigned short u16x8 __attribute__((ext_vector_type(8)));

__device__ inline unsigned short f2bf(float x){
  unsigned int u = __builtin_bit_cast(unsigned int, x);
  u += 0x7fffu + ((u >> 16) & 1u);
  return (unsigned short)(u >> 16);
}
__device__ inline float bf2f(unsigned short h){
  unsigned int u = ((unsigned int)h) << 16;
  return __builtin_bit_cast(float, u);
}
__device__ inline void atomic_add_f(float* p, float v){
  __hip_atomic_fetch_add(p, v, __ATOMIC_RELAXED, __HIP_MEMORY_SCOPE_AGENT);
}
__device__ inline void gload16(const void* g, void* l){
  __builtin_amdgcn_global_load_lds(
      (const __attribute__((address_space(1))) unsigned int*)g,
      (__attribute__((address_space(3))) unsigned int*)l, 16, 0, 0);
}
__device__ inline float silu(float x){ return x / (1.f + __expf(-x)); }

__device__ inline void build_qp(unsigned short* qp, int tid){
  if (tid < 40){
    int q = tid;
    int m0 = q * 40 - (q * (q - 1)) / 2;
    for (int p = q; p < 40; p++) qp[m0 + p - q] = (unsigned short)((q << 8) | p);
  }
}

__device__ inline int block_scan_excl(int v, int tid, int* lds){
  int lane = tid & 63, w = tid >> 6;
  int x = v;
  #pragma unroll
  for (int d = 1; d < 64; d <<= 1){
    int y = __shfl_up(x, d, 64);
    if (lane >= d) x += y;
  }
  if (lane == 63) lds[w] = x;
  __syncthreads();
  int wsum = 0;
  for (int i = 0; i < w; i++) wsum += lds[i];
  return wsum + x - v;
}

// ---------------- edge counting sort by key = recv*4 + species(sender) ----------------
__global__ __launch_bounds__(256) void k_hist(const int* __restrict__ ei,
                                              const int* __restrict__ numbers,
                                              int* __restrict__ cnt64k){
  int e = blockIdx.x * 256 + threadIdx.x;
  if (e < NE){
    int key = ei[NE + e] * 4 + numbers[ei[e]];
    atomicAdd(&cnt64k[key], 1);
  }
}

__global__ __launch_bounds__(256) void k_scanA(const int* __restrict__ cnt64k,
                                               int* __restrict__ bsum){
  __shared__ int lds[4];
  int tid = threadIdx.x;
  int v = cnt64k[blockIdx.x * 256 + tid];
  int lane = tid & 63;
  #pragma unroll
  for (int m = 32; m; m >>= 1) v += __shfl_xor(v, m, 64);
  if (lane == 0) lds[tid >> 6] = v;
  __syncthreads();
  if (tid == 0) bsum[blockIdx.x] = lds[0] + lds[1] + lds[2] + lds[3];
}

__global__ __launch_bounds__(256) void k_scanB(const int* __restrict__ bsum,
                                               int* __restrict__ boff, int* __restrict__ starts){
  __shared__ int lds[4];
  int tid = threadIdx.x;
  int v = bsum[tid];
  int e = block_scan_excl(v, tid, lds);
  boff[tid] = e;
  if (tid == 0) starts[65536] = NE;
}

__global__ __launch_bounds__(256) void k_scanC(const int* __restrict__ cnt64k,
                                               const int* __restrict__ boff,
                                               int* __restrict__ starts, int* __restrict__ cursor){
  __shared__ int lds[4];
  int tid = threadIdx.x;
  int bin = blockIdx.x * 256 + tid;
  int v = cnt64k[bin];
  int e = block_scan_excl(v, tid, lds) + boff[blockIdx.x];
  starts[bin] = e;
  cursor[bin] = e;
}

__global__ __launch_bounds__(256) void k_sortperm(const int* __restrict__ ei,
                                                  const int* __restrict__ numbers,
                                                  int* __restrict__ cursor, int* __restrict__ perm){
  int e = blockIdx.x * 256 + threadIdx.x;
  if (e < NE){
    int key = ei[NE + e] * 4 + numbers[ei[e]];
    int p = atomicAdd(&cursor[key], 1);
    perm[p] = e;
  }
}

// ---------------- species grouping of atoms (contention-free counting sort) -----------
__global__ __launch_bounds__(256) void k_acount(const int* __restrict__ numbers,
                                                int* __restrict__ bhist){
  __shared__ int h[4];
  int tid = threadIdx.x;
  if (tid < 4) h[tid] = 0;
  __syncthreads();
  atomicAdd(&h[numbers[blockIdx.x * 256 + tid]], 1);
  __syncthreads();
  if (tid < 4) bhist[blockIdx.x * 4 + tid] = h[tid];
}

__global__ void k_aoffs(const int* __restrict__ bhist, int* __restrict__ boffs,
                        int* __restrict__ ints){
  if (threadIdx.x == 0){
    int* cnt = ints; int* offs = ints + 8;
    int tot[4] = {0,0,0,0};
    for (int b = 0; b < 64; b++)
      for (int s = 0; s < 4; s++) tot[s] += bhist[b*4 + s];
    int o = 0;
    for (int s = 0; s < 4; s++){ cnt[s] = tot[s]; offs[s] = o; o += tot[s]; }
    offs[4] = o;
    int run[4];
    for (int s = 0; s < 4; s++) run[s] = offs[s];
    for (int b = 0; b < 64; b++)
      for (int s = 0; s < 4; s++){ boffs[b*4 + s] = run[s]; run[s] += bhist[b*4 + s]; }
  }
}

__global__ __launch_bounds__(256) void k_aplace(const int* __restrict__ numbers,
                                                const int* __restrict__ boffs,
                                                int* __restrict__ list){
  __shared__ int ws[4][4];
  int tid = threadIdx.x, w = tid >> 6, lane = tid & 63;
  int i = blockIdx.x * 256 + tid;
  int sp = numbers[i];
  int rank = 0;
  #pragma unroll
  for (int s = 0; s < 4; s++){
    unsigned long long m = __ballot(sp == s);
    if (s == sp) rank = __popcll(m & (((unsigned long long)1 << lane) - 1));
    if (lane == 0) ws[w][s] = __popcll(m);
  }
  __syncthreads();
  int pre = 0;
  for (int w2 = 0; w2 < w; w2++) pre += ws[w2][sp];
  list[boffs[blockIdx.x * 4 + sp] + pre + rank] = i;
}

// ---------------- per-edge geometry (fully parallel, sorted order): ef[19][NE] --------
__global__ __launch_bounds__(256) void k_egeom(
    const float* __restrict__ pos, const float* __restrict__ cells,
    const int* __restrict__ ei, const float* __restrict__ eoff,
    const int* __restrict__ batch, const int* __restrict__ perm,
    float* __restrict__ ef)
{
  int i = blockIdx.x * 256 + threadIdx.x;
  if (i >= NE) return;
  int e = perm[i];
  int snd = ei[e], rcv = ei[NE + e];
  const float* C = cells + (size_t)batch[snd] * 9;
  float o0 = eoff[e*3+0], o1 = eoff[e*3+1], o2 = eoff[e*3+2];
  float rx = pos[rcv*3+0] - pos[snd*3+0] + o0*C[0] + o1*C[3] + o2*C[6];
  float ry = pos[rcv*3+1] - pos[snd*3+1] + o0*C[1] + o1*C[4] + o2*C[7];
  float rz = pos[rcv*3+2] - pos[snd*3+2] + o0*C[2] + o1*C[5] + o2*C[8];
  float r = sqrtf(rx*rx + ry*ry + rz*rz + 1e-12f);
  float inv = 1.f / r;
  float hx = rx*inv, hy = ry*inv, hz = rz*inv;
  float fc = (r < 5.f) ? (0.5f * (__cosf(r * 0.6283185307179586f) + 1.f)) : 0.f;
  #pragma unroll
  for (int nn = 0; nn < NMX; nn++){
    float d = r - (5.f/9.f) * (float)nn;
    ef[(size_t)nn * NE + i] = __expf(-2.f * d * d) * fc;
  }
  ef[(size_t)10 * NE + i] = 0.28209479177387814f;
  ef[(size_t)11 * NE + i] = 0.4886025119029199f * hy;
  ef[(size_t)12 * NE + i] = 0.4886025119029199f * hz;
  ef[(size_t)13 * NE + i] = 0.4886025119029199f * hx;
  ef[(size_t)14 * NE + i] = 1.0925484305920792f * hx * hy;
  ef[(size_t)15 * NE + i] = 1.0925484305920792f * hy * hz;
  ef[(size_t)16 * NE + i] = 0.31539156525252005f * (3.f * hz * hz - 1.f);
  ef[(size_t)17 * NE + i] = 1.0925484305920792f * hx * hz;
  ef[(size_t)18 * NE + i] = 0.5462742152960396f * (hx * hx - hy * hy);
}

// ---------------- per-atom: ef accumulate -> U-mix -> FOLDED ps + weighted stats ------
__global__ __launch_bounds__(384) void k_atom2(
    const float* __restrict__ ef, const int* __restrict__ startsK,
    const float* __restrict__ U,
    unsigned short* __restrict__ ps, float* __restrict__ stats)
{
  __shared__ float efl[64][21];   // [edge][component], stride 21 -> conflict-free
  __shared__ float csr[360];
  __shared__ float cl[360];
  __shared__ float red[16];
  __shared__ float ul[16];
  __shared__ unsigned short qp[NPAIR];
  int atom = blockIdx.x;
  int tid = threadIdx.x;
  if (tid < 16) ul[tid] = U[tid];
  build_qp(qp, tid);
  int e0 = startsK[atom * 4], e1 = startsK[atom * 4 + 4];
  int sp = tid / 90, n = (tid % 90) / 9, k = tid % 9;
  int aS = 0, aE = 0;
  if (tid < 360){ aS = startsK[atom * 4 + sp]; aE = startsK[atom * 4 + sp + 1]; }
  float acc = 0.f;
  for (int base = e0; base < e1; base += 64){
    int nch = min(64, e1 - base);
    for (int idx = tid; idx < 19 * 64; idx += 384){
      int j = idx >> 6, ln = idx & 63;
      float v = 0.f;
      if (ln < nch) v = ef[(size_t)j * NE + base + ln];
      efl[ln][j] = v;
    }
    __syncthreads();
    if (tid < 360){
      int lo2 = max(aS, base), hi2 = min(aE, base + nch);
      for (int e = lo2; e < hi2; e++){
        int j = e - base;
        acc += efl[j][n] * efl[j][10 + k];
      }
    }
    __syncthreads();
  }
  if (tid < 360) csr[tid] = acc;
  __syncthreads();
  if (tid < 360){
    int a = tid / 90, nk = tid % 90;
    cl[tid] = ul[a*4+0]*csr[nk] + ul[a*4+1]*csr[90+nk]
            + ul[a*4+2]*csr[180+nk] + ul[a*4+3]*csr[270+nk];
  }
  __syncthreads();
  float s1 = 0.f, s2 = 0.f;
  if (tid < 312){
    int chunk = tid;
    int l = (chunk >= 208) ? 2 : ((chunk >= 104) ? 1 : 0);
    int m0 = (chunk - l * 104) * 8;
    unsigned short o[8];
    #pragma unroll
    for (int j = 0; j < 8; j++){
      int m = m0 + j;
      float v = 0.f, wgt = 0.f;
      if (m < NPAIR){
        int q = qp[m] >> 8, p = qp[m] & 255;
        const float* cq = &cl[q * 9];
        const float* cp = &cl[p * 9];
        if (l == 0)      v = cq[0]*cp[0];
        else if (l == 1) v = (cq[1]*cp[1] + cq[2]*cp[2] + cq[3]*cp[3]) * 0.5773502691896258f;
        else             v = (cq[4]*cp[4] + cq[5]*cp[5] + cq[6]*cp[6] + cq[7]*cp[7] + cq[8]*cp[8]) * 0.4472135954999579f;
        wgt = (p != q) ? 2.f : 1.f;
      }
      o[j] = f2bf(v);
      s1 += wgt * v; s2 += wgt * v * v;
    }
    *reinterpret_cast<u16x8*>(ps + (size_t)atom * FR + chunk * 8) = *(const u16x8*)o;
  }
  #pragma unroll
  for (int m = 32; m; m >>= 1){ s1 += __shfl_xor(s1, m, 64); s2 += __shfl_xor(s2, m, 64); }
  int w = tid >> 6, lane = tid & 63;
  if (lane == 0){ red[w] = s1; red[8 + w] = s2; }
  __syncthreads();
  if (tid == 0){
    float t1 = 0.f, t2 = 0.f;
    for (int i = 0; i < 6; i++){ t1 += red[i]; t2 += red[8 + i]; }
    float mean = t1 * (1.f / FF);
    float var = t2 * (1.f / FF) - mean * mean;
    var = fmaxf(var, 0.f);
    stats[2*atom]   = mean;
    stats[2*atom+1] = rsqrtf(var + 1e-5f);
  }
}

// ---------------- weight prep: FOLDED Wg[s][n][f'], f' = l*832 + pair m ---------------
__global__ __launch_bounds__(256) void k_wg1(
    const float* __restrict__ W1, const float* __restrict__ U,
    const float* __restrict__ gamma, const float* __restrict__ beta,
    unsigned short* __restrict__ Wg, float* __restrict__ gW, float* __restrict__ bW)
{
  __shared__ float tg[64][65];
  __shared__ float tb[64][65];
  __shared__ unsigned short qp[NPAIR];
  int n0 = blockIdx.x * 64, f0 = blockIdx.y * 64, s = blockIdx.z;
  int l = blockIdx.y / 13;
  int mblk = (blockIdx.y - l * 13) * 64;
  float u0 = U[s], u1 = U[4+s], u2 = U[8+s], u3 = U[12+s];
  int tid = threadIdx.x;
  build_qp(qp, tid);
  __syncthreads();
  #pragma unroll 4
  for (int rep = 0; rep < 16; rep++){
    int idx = rep * 256 + tid;
    int fi = idx >> 6, ni = idx & 63;
    int m = mblk + fi;
    float tgv = 0.f, tbv = 0.f;
    if (m < NPAIR){
      int q = qp[m] >> 8, p = qp[m] & 255;
      int fa = (q * 40 + p) * 3 + l;
      size_t basea = (size_t)fa * 512 + (n0 + ni);
      float wa = u0*W1[basea] + u1*W1[basea + (size_t)FF*512]
               + u2*W1[basea + (size_t)2*FF*512] + u3*W1[basea + (size_t)3*FF*512];
      tgv = gamma[fa] * wa;
      tbv = beta[fa] * wa;
      if (p != q){
        int fb = (p * 40 + q) * 3 + l;
        size_t baseb = (size_t)fb * 512 + (n0 + ni);
        float wb = u0*W1[baseb] + u1*W1[baseb + (size_t)FF*512]
                 + u2*W1[baseb + (size_t)2*FF*512] + u3*W1[baseb + (size_t)3*FF*512];
        tgv += gamma[fb] * wb;
        tbv += beta[fb] * wb;
      }
    }
    tg[fi][ni] = tgv;
    tb[fi][ni] = tbv;
  }
  __syncthreads();
  #pragma unroll 4
  for (int rep = 0; rep < 16; rep++){
    int idx = rep * 256 + tid;
    int ni = idx >> 6, fi = idx & 63;
    Wg[((size_t)s * 512 + n0 + ni) * FR + f0 + fi] = f2bf(tg[fi][ni]);
  }
  if (tid < 64){
    float sg = 0.f, sb = 0.f;
    for (int fi = 0; fi < 64; fi++){ sg += tg[fi][tid]; sb += tb[fi][tid]; }
    atomic_add_f(&gW[s * 512 + n0 + tid], sg);
    atomic_add_f(&bW[s * 512 + n0 + tid], sb);
  }
}

__global__ __launch_bounds__(256) void k_w2t(
    const float* __restrict__ W2, const float* __restrict__ U,
    unsigned short* __restrict__ W2t)
{
  __shared__ float t[64][65];
  int n0 = blockIdx.x * 64, k0 = blockIdx.y * 64, s = blockIdx.z;
  float u0 = U[s], u1 = U[4+s], u2 = U[8+s], u3 = U[12+s];
  int tid = threadIdx.x;
  #pragma unroll 4
  for (int rep = 0; rep < 16; rep++){
    int idx = rep * 256 + tid;
    int ki = idx >> 6, ni = idx & 63;
    size_t base = (size_t)(k0 + ki) * 512 + (n0 + ni);
    t[ki][ni] = u0*W2[base] + u1*W2[base + 512*512]
              + u2*W2[base + 2*512*512] + u3*W2[base + 3*512*512];
  }
  __syncthreads();
  #pragma unroll 4
  for (int rep = 0; rep < 16; rep++){
    int idx = rep * 256 + tid;
    int ni = idx >> 6, ki = idx & 63;
    W2t[((size_t)s * 512 + n0 + ni) * 512 + k0 + ki] = f2bf(t[ki][ni]);
  }
}

__global__ void k_w3(const float* __restrict__ W3, const float* __restrict__ U,
                     float* __restrict__ W3s)
{
  int idx = blockIdx.x * 256 + threadIdx.x;
  if (idx < 4 * 512){
    int s = idx >> 9, k = idx & 511;
    W3s[idx] = U[s]*W3[k] + U[4+s]*W3[512+k] + U[8+s]*W3[2*512+k] + U[12+s]*W3[3*512+k];
  }
}

// ---------------- GEMM template (128x128 tile, BK=64, bf16 MFMA) ----------------
template<int EPI, int NSPLIT>
__global__ __launch_bounds__(256) void k_gemm(
    const unsigned short* __restrict__ Ag, int lda, int K,
    const unsigned short* __restrict__ Btg,
    const int* __restrict__ list, const int* __restrict__ offs, const int* __restrict__ cnt,
    unsigned short* __restrict__ pout,
    const float* __restrict__ W3s, float* __restrict__ pacc)
{
  __shared__ alignas(16) char smem[32768];
  const int NV = 4 * NSPLIT;
  int b = blockIdx.x;
  int y = (b & 7) + 8 * (b / (8 * NV));
  int v = (b >> 3) % NV;
  int x = v & 3, kh = v >> 2;

  int s = 0, t = y;
  for (; s < 4; s++){
    int nts = (cnt[s] + 127) >> 7;
    if (t < nts) break;
    t -= nts;
  }
  if (s >= 4) return;
  int cntS = cnt[s], offS = offs[s];
  int rt = t, n0 = x * 128;
  int tid = threadIdx.x, w = tid >> 6, lane = tid & 63;
  int wr = w >> 1, wc = w & 1;

  const unsigned short* Bts = Btg + (size_t)s * 512 * K;
  const unsigned short* gA[4];
  const unsigned short* gB[4];
  char* lA[4];
  char* lB[4];
  #pragma unroll
  for (int it = 0; it < 4; it++){
    int g = it * 4 + w;
    int idx = g * 64 + lane;
    int row = idx >> 3, ch = idx & 7;
    int cg = ch ^ (row & 7);
    int gr = rt * 128 + row; gr = gr < cntS ? gr : cntS - 1;
    int atom = list[offS + gr];
    gA[it] = Ag + (size_t)atom * lda + cg * 8;
    lA[it] = smem + g * 1024;
    gB[it] = Bts + (size_t)(n0 + row) * K + cg * 8;
    lB[it] = smem + 16384 + g * 1024;
  }

  int hi = lane >> 4, lo = lane & 15;
  f32x4 acc[4][4];
  #pragma unroll
  for (int mi = 0; mi < 4; mi++)
    #pragma unroll
    for (int ni = 0; ni < 4; ni++)
      #pragma unroll
      for (int r = 0; r < 4; r++) acc[mi][ni][r] = 0.f;

  int abase[4], a7[4], bbase[4], b7[4];
  #pragma unroll
  for (int mi = 0; mi < 4; mi++){ int row = wr*64 + mi*16 + lo; abase[mi] = row*128; a7[mi] = row & 7; }
  #pragma unroll
  for (int ni = 0; ni < 4; ni++){ int row = wc*64 + ni*16 + lo; bbase[ni] = 16384 + row*128; b7[ni] = row & 7; }

  int nk = K / 64;
  int k0 = ((nk * kh) / NSPLIT) * 64;
  int k1 = ((nk * (kh + 1)) / NSPLIT) * 64;

  for (int kt = k0; kt < k1; kt += 64){
    #pragma unroll
    for (int it = 0; it < 4; it++) gload16(gA[it] + kt, lA[it]);
    #pragma unroll
    for (int it = 0; it < 4; it++) gload16(gB[it] + kt, lB[it]);
    __syncthreads();
    #pragma unroll
    for (int kk = 0; kk < 2; kk++){
      bf16x8 af[4], bfr[4];
      #pragma unroll
      for (int mi = 0; mi < 4; mi++)
        af[mi] = *(const bf16x8*)(smem + abase[mi] + (((kk*4 + hi) ^ a7[mi]) << 4));
      #pragma unroll
      for (int ni = 0; ni < 4; ni++)
        bfr[ni] = *(const bf16x8*)(smem + bbase[ni] + (((kk*4 + hi) ^ b7[ni]) << 4));
      #pragma unroll
      for (int mi = 0; mi < 4; mi++)
        #pragma unroll
        for (int ni = 0; ni < 4; ni++)
          acc[mi][ni] = __builtin_amdgcn_mfma_f32_16x16x32_bf16(af[mi], bfr[ni], acc[mi][ni], 0, 0, 0);
    }
    __syncthreads();
  }

  int gn[4];
  #pragma unroll
  for (int ni = 0; ni < 4; ni++) gn[ni] = n0 + wc*64 + ni*16 + lo;

  if (EPI == 0){
    #pragma unroll
    for (int mi = 0; mi < 4; mi++){
      #pragma unroll
      for (int j = 0; j < 4; j++){
        int gr = rt*128 + wr*64 + mi*16 + hi*4 + j;
        if (gr < cntS){
          int atom = list[offS + gr];
          #pragma unroll
          for (int ni = 0; ni < 4; ni++)
            pout[((size_t)kh * NA + atom) * 512 + gn[ni]] = f2bf(acc[mi][ni][j]);
        }
      }
    }
  } else {
    float w3v[4];
    #pragma unroll
    for (int ni = 0; ni < 4; ni++) w3v[ni] = W3s[s * 512 + gn[ni]];
    float* pslot = pacc + (size_t)(x * 2 + wc) * NA;
    #pragma unroll
    for (int mi = 0; mi < 4; mi++){
      #pragma unroll
      for (int j = 0; j < 4; j++){
        int gr = rt*128 + wr*64 + mi*16 + hi*4 + j;
        if (gr < cntS){
          int atom = list[offS + gr];
          float pdot = 0.f;
          #pragma unroll
          for (int ni = 0; ni < 4; ni++)
            pdot += silu(acc[mi][ni][j]) * w3v[ni];
          pdot += __shfl_xor(pdot, 1, 16);
          pdot += __shfl_xor(pdot, 2, 16);
          pdot += __shfl_xor(pdot, 4, 16);
          pdot += __shfl_xor(pdot, 8, 16);
          if (lo == 0) pslot[atom] = pdot;
        }
      }
    }
  }
}

// ---------------- epilogue: combine split-K partials + LN-affine + silu -> h1 ---------
__global__ __launch_bounds__(256) void k_epi(
    const unsigned short* __restrict__ pbuf, const float* __restrict__ stats,
    const float* __restrict__ gW, const float* __restrict__ bW,
    const int* __restrict__ numbers, unsigned short* __restrict__ h1)
{
  int w = threadIdx.x >> 6, lane = threadIdx.x & 63;
  int atom = blockIdx.x * 4 + w;
  int s = numbers[atom];
  float mean = stats[2*atom], rstd = stats[2*atom+1];
  int c0 = lane * 8;
  u16x8 a0 = *reinterpret_cast<const u16x8*>(pbuf + (size_t)atom * 512 + c0);
  u16x8 a1 = *reinterpret_cast<const u16x8*>(pbuf + (size_t)(NA + atom) * 512 + c0);
  unsigned short o[8];
  #pragma unroll
  for (int j = 0; j < 8; j++){
    int c = c0 + j;
    float acc = bf2f(a0[j]) + bf2f(a1[j]);
    float vv = rstd * acc + bW[s*512 + c] - mean * rstd * gW[s*512 + c];
    o[j] = f2bf(silu(vv));
  }
  *reinterpret_cast<u16x8*>(h1 + (size_t)atom * 512 + c0) = *(const u16x8*)o;
}

// ---------------- final: sum 8 pacc partials/atom, wave-uniform molecule atomic -------
__global__ __launch_bounds__(256) void k_final2(
    const float* __restrict__ pacc, const int* __restrict__ numbers,
    const int* __restrict__ batch, const float* __restrict__ Wc,
    float* __restrict__ molOut)
{
  int atom = blockIdx.x * 256 + threadIdx.x;
  int lane = threadIdx.x & 63;
  float sum = 0.f;
  #pragma unroll
  for (int p = 0; p < 8; p++) sum += pacc[(size_t)p * NA + atom];
  float val = sum * (1.f / 128.f) + Wc[numbers[atom]];
  int mol = batch[atom];
  int m0 = __shfl(mol, 0, 64);
  int m63 = __shfl(mol, 63, 64);
  if (m0 == m63){
    #pragma unroll
    for (int m = 32; m; m >>= 1) val += __shfl_xor(val, m, 64);
    if (lane == 0) atomic_add_f(&molOut[mol], val);
  } else {
    atomic_add_f(&molOut[mol], val);
  }
}

extern "C" void kernel_launch(void* const* d_in, const int* in_sizes, int n_in,
                              void* d_out, int out_size, void* d_ws, size_t ws_size,
                              hipStream_t stream)
{
  const float* pos     = (const float*)d_in[0];
  const float* cells   = (const float*)d_in[1];
  const int*   numbers = (const int*)d_in[2];
  const int*   ei      = (const int*)d_in[3];
  const float* eoff    = (const float*)d_in[4];
  const int*   batch   = (const int*)d_in[5];
  const float* U       = (const float*)d_in[6];
  const float* gamma   = (const float*)d_in[7];
  const float* beta    = (const float*)d_in[8];
  const float* W1      = (const float*)d_in[9];
  const float* W2      = (const float*)d_in[10];
  const float* W3      = (const float*)d_in[11];
  const float* Wc      = (const float*)d_in[12];
  float* out = (float*)d_out;

  char* ws = (char*)d_ws;
  size_t off = 0;
  auto alloc = [&](size_t bytes) -> void* {
    void* p = ws + off;
    off += (bytes + 255) & ~(size_t)255;
    return p;
  };
  unsigned short* ps   = (unsigned short*)alloc((size_t)NA * FR * 2);      // 78 MB
  float* ef            = (float*)alloc((size_t)19 * NE * 4);               // 39.8 MB
  unsigned short* pbuf = (unsigned short*)alloc((size_t)2 * NA * 512 * 2); // 32 MB
  float* stats         = (float*)alloc((size_t)NA * 2 * 4);
  unsigned short* Wg1  = (unsigned short*)alloc((size_t)4 * 512 * FR * 2); // 10.2 MB
  float* gW            = (float*)alloc(4 * 512 * 4);
  float* bW            = (float*)alloc(4 * 512 * 4);
  unsigned short* W2t  = (unsigned short*)alloc((size_t)4 * 512 * 512 * 2);
  float* W3s           = (float*)alloc(4 * 512 * 4);
  unsigned short* h1   = (unsigned short*)alloc((size_t)NA * 512 * 2);
  float* pacc          = (float*)alloc((size_t)8 * NA * 4);
  int* list            = (int*)alloc(NA * 4);
  int* perm            = (int*)alloc((size_t)NE * 4);
  int* startsK         = (int*)alloc((65536 + 1) * 4);
  int* cnt64k          = (int*)alloc(65536 * 4);
  int* cursor64k       = (int*)alloc(65536 * 4);
  int* bsum            = (int*)alloc(256 * 4);
  int* boff            = (int*)alloc(256 * 4);
  int* bhist           = (int*)alloc(64 * 4 * 4);
  int* boffs           = (int*)alloc(64 * 4 * 4);
  int* ints            = (int*)alloc(64);
  int* cnt = ints; int* offs = ints + 8;

  hipMemsetAsync(cnt64k, 0, 65536 * 4, stream);
  hipMemsetAsync(gW, 0, 4 * 512 * 4, stream);
  hipMemsetAsync(bW, 0, 4 * 512 * 4, stream);
  hipMemsetAsync(out, 0, (size_t)out_size * 4, stream);

  // edge counting sort by (recv, sender-species)
  k_hist<<<NE / 256, 256, 0, stream>>>(ei, numbers, cnt64k);
  k_scanA<<<256, 256, 0, stream>>>(cnt64k, bsum);
  k_scanB<<<1, 256, 0, stream>>>(bsum, boff, startsK);
  k_scanC<<<256, 256, 0, stream>>>(cnt64k, boff, startsK, cursor64k);
  k_sortperm<<<NE / 256, 256, 0, stream>>>(ei, numbers, cursor64k, perm);

  // atom species grouping: contention-free stable counting sort
  k_acount<<<NA / 256, 256, 0, stream>>>(numbers, bhist);
  k_aoffs<<<1, 64, 0, stream>>>(bhist, boffs, ints);
  k_aplace<<<NA / 256, 256, 0, stream>>>(numbers, boffs, list);

  // per-edge geometry (parallel) then per-atom accumulate + folded ps + stats
  k_egeom<<<NE / 256, 256, 0, stream>>>(pos, cells, ei, eoff, batch, perm, ef);
  k_atom2<<<NA, 384, 0, stream>>>(ef, startsK, U, ps, stats);

  // weight prep (folded K = 2496)
  k_wg1<<<dim3(8, 39, 4), 256, 0, stream>>>(W1, U, gamma, beta, Wg1, gW, bW);
  k_w2t<<<dim3(8, 8, 4), 256, 0, stream>>>(W2, U, W2t);
  k_w3<<<8, 256, 0, stream>>>(W3, U, W3s);

  // GEMM1 split-K=2 (K=2496), then LN+silu epilogue
  k_gemm<0, 2><<<1088, 256, 0, stream>>>(ps, FR, FR, Wg1, list, offs, cnt,
                                         pbuf, nullptr, nullptr);
  k_epi<<<NA / 4, 256, 0, stream>>>(pbuf, stats, gW, bW, numbers, h1);

  // GEMM2 with fused silu + W3 dot -> per-atom partials (atomic-free)
  k_gemm<2, 1><<<544, 256, 0, stream>>>(h1, 512, 512, W2t, list, offs, cnt,
                                        nullptr, W3s, pacc);
  k_final2<<<NA / 256, 256, 0, stream>>>(pacc, numbers, batch, Wc, out);
}

// Round 12
// 358.764 us; speedup vs baseline: 1.0104x; 1.0104x over previous
//
#include <hip/hip_runtime.h>

#define NA   16384
#define NE   524288
#define NM   256
#define FF   4800
#define FR   2496   // folded K: 3*832 slots, layout f' = 3*m + l (m = pair, 820 valid)
#define NPAIR 820
#define HH   512
#define NMX  10
#define NSPH 9

typedef __bf16 bf16x8 __attribute__((ext_vector_type(8)));
typedef float  f32x4  __attribute__((ext_vector_type(4)));
typedef unsigned short u16x8 __attribute__((ext_vector_type(8)));

__device__ inline unsigned short f2bf(float x){
  unsigned int u = __builtin_bit_cast(unsigned int, x);
  u += 0x7fffu + ((u >> 16) & 1u);
  return (unsigned short)(u >> 16);
}
__device__ inline float bf2f(unsigned short h){
  unsigned int u = ((unsigned int)h) << 16;
  return __builtin_bit_cast(float, u);
}
__device__ inline void atomic_add_f(float* p, float v){
  __hip_atomic_fetch_add(p, v, __ATOMIC_RELAXED, __HIP_MEMORY_SCOPE_AGENT);
}
__device__ inline void gload16(const void* g, void* l){
  __builtin_amdgcn_global_load_lds(
      (const __attribute__((address_space(1))) unsigned int*)g,
      (__attribute__((address_space(3))) unsigned int*)l, 16, 0, 0);
}
__device__ inline float silu(float x){ return x / (1.f + __expf(-x)); }

__device__ inline void build_qp(unsigned short* qp, int tid){
  if (tid < 40){
    int q = tid;
    int m0 = q * 40 - (q * (q - 1)) / 2;
    for (int p = q; p < 40; p++) qp[m0 + p - q] = (unsigned short)((q << 8) | p);
  }
}

__device__ inline int block_scan_excl(int v, int tid, int* lds){
  int lane = tid & 63, w = tid >> 6;
  int x = v;
  #pragma unroll
  for (int d = 1; d < 64; d <<= 1){
    int y = __shfl_up(x, d, 64);
    if (lane >= d) x += y;
  }
  if (lane == 63) lds[w] = x;
  __syncthreads();
  int wsum = 0;
  for (int i = 0; i < w; i++) wsum += lds[i];
  return wsum + x - v;
}

// ---------------- edge counting sort by key = recv*4 + species(sender) ----------------
__global__ __launch_bounds__(256) void k_hist(const int* __restrict__ ei,
                                              const int* __restrict__ numbers,
                                              int* __restrict__ cnt64k){
  int e = blockIdx.x * 256 + threadIdx.x;
  if (e < NE){
    int key = ei[NE + e] * 4 + numbers[ei[e]];
    atomicAdd(&cnt64k[key], 1);
  }
}

__global__ __launch_bounds__(256) void k_scanA(const int* __restrict__ cnt64k,
                                               int* __restrict__ bsum){
  __shared__ int lds[4];
  int tid = threadIdx.x;
  int v = cnt64k[blockIdx.x * 256 + tid];
  int lane = tid & 63;
  #pragma unroll
  for (int m = 32; m; m >>= 1) v += __shfl_xor(v, m, 64);
  if (lane == 0) lds[tid >> 6] = v;
  __syncthreads();
  if (tid == 0) bsum[blockIdx.x] = lds[0] + lds[1] + lds[2] + lds[3];
}

__global__ __launch_bounds__(256) void k_scanB(const int* __restrict__ bsum,
                                               int* __restrict__ boff, int* __restrict__ starts){
  __shared__ int lds[4];
  int tid = threadIdx.x;
  int v = bsum[tid];
  int e = block_scan_excl(v, tid, lds);
  boff[tid] = e;
  if (tid == 0) starts[65536] = NE;
}

__global__ __launch_bounds__(256) void k_scanC(const int* __restrict__ cnt64k,
                                               const int* __restrict__ boff,
                                               int* __restrict__ starts, int* __restrict__ cursor){
  __shared__ int lds[4];
  int tid = threadIdx.x;
  int bin = blockIdx.x * 256 + tid;
  int v = cnt64k[bin];
  int e = block_scan_excl(v, tid, lds) + boff[blockIdx.x];
  starts[bin] = e;
  cursor[bin] = e;
}

__global__ __launch_bounds__(256) void k_sortperm(const int* __restrict__ ei,
                                                  const int* __restrict__ numbers,
                                                  int* __restrict__ cursor, int* __restrict__ perm){
  int e = blockIdx.x * 256 + threadIdx.x;
  if (e < NE){
    int key = ei[NE + e] * 4 + numbers[ei[e]];
    int p = atomicAdd(&cursor[key], 1);
    perm[p] = e;
  }
}

// ---------------- species grouping of atoms (contention-free counting sort) -----------
__global__ __launch_bounds__(256) void k_acount(const int* __restrict__ numbers,
                                                int* __restrict__ bhist){
  __shared__ int h[4];
  int tid = threadIdx.x;
  if (tid < 4) h[tid] = 0;
  __syncthreads();
  atomicAdd(&h[numbers[blockIdx.x * 256 + tid]], 1);
  __syncthreads();
  if (tid < 4) bhist[blockIdx.x * 4 + tid] = h[tid];
}

__global__ void k_aoffs(const int* __restrict__ bhist, int* __restrict__ boffs,
                        int* __restrict__ ints){
  if (threadIdx.x == 0){
    int* cnt = ints; int* offs = ints + 8;
    int tot[4] = {0,0,0,0};
    for (int b = 0; b < 64; b++)
      for (int s = 0; s < 4; s++) tot[s] += bhist[b*4 + s];
    int o = 0;
    for (int s = 0; s < 4; s++){ cnt[s] = tot[s]; offs[s] = o; o += tot[s]; }
    offs[4] = o;
    int run[4];
    for (int s = 0; s < 4; s++) run[s] = offs[s];
    for (int b = 0; b < 64; b++)
      for (int s = 0; s < 4; s++){ boffs[b*4 + s] = run[s]; run[s] += bhist[b*4 + s]; }
  }
}

__global__ __launch_bounds__(256) void k_aplace(const int* __restrict__ numbers,
                                                const int* __restrict__ boffs,
                                                int* __restrict__ list){
  __shared__ int ws[4][4];
  int tid = threadIdx.x, w = tid >> 6, lane = tid & 63;
  int i = blockIdx.x * 256 + tid;
  int sp = numbers[i];
  int rank = 0;
  #pragma unroll
  for (int s = 0; s < 4; s++){
    unsigned long long m = __ballot(sp == s);
    if (s == sp) rank = __popcll(m & (((unsigned long long)1 << lane) - 1));
    if (lane == 0) ws[w][s] = __popcll(m);
  }
  __syncthreads();
  int pre = 0;
  for (int w2 = 0; w2 < w; w2++) pre += ws[w2][sp];
  list[boffs[blockIdx.x * 4 + sp] + pre + rank] = i;
}

// ---------------- fused per-atom (512 thr): geometry -> species-uniform accumulate ->
//                  U-mix -> pair-major folded ps (f'=3m+l) + weighted LN stats ---------
__global__ __launch_bounds__(512) void k_atom3(
    const float* __restrict__ pos, const float* __restrict__ cells,
    const int* __restrict__ ei, const float* __restrict__ eoff,
    const int* __restrict__ batch, const int* __restrict__ startsK,
    const int* __restrict__ perm, const float* __restrict__ U,
    unsigned short* __restrict__ ps, float* __restrict__ stats)
{
  __shared__ float Rl[128][NMX];
  __shared__ float Yl[128][NSPH];
  __shared__ float csr[360];
  __shared__ float cl[360];
  __shared__ float red[16];
  __shared__ float ul[16];
  __shared__ unsigned short qp[NPAIR];
  int atom = blockIdx.x;
  int tid = threadIdx.x;
  if (tid < 16) ul[tid] = U[tid];
  build_qp(qp, tid);
  int e0 = startsK[atom * 4], e1 = startsK[atom * 4 + 4];
  float px = pos[atom*3+0], py = pos[atom*3+1], pz = pos[atom*3+2];
  int sp = tid >> 7, nk = tid & 127;      // species-uniform waves
  int n = nk / 9, k = nk - n * 9;         // valid when nk < 90
  int aS = startsK[atom * 4 + sp], aE = startsK[atom * 4 + sp + 1];
  float acc = 0.f;
  for (int base = e0; base < e1; base += 128){
    int nch = min(128, e1 - base);
    if (tid < nch){
      int e = perm[base + tid];
      int snd = ei[e];
      const float* C = cells + (size_t)batch[snd] * 9;
      float o0 = eoff[e*3+0], o1 = eoff[e*3+1], o2 = eoff[e*3+2];
      float rx = px - pos[snd*3+0] + o0*C[0] + o1*C[3] + o2*C[6];
      float ry = py - pos[snd*3+1] + o0*C[1] + o1*C[4] + o2*C[7];
      float rz = pz - pos[snd*3+2] + o0*C[2] + o1*C[5] + o2*C[8];
      float r = sqrtf(rx*rx + ry*ry + rz*rz + 1e-12f);
      float inv = 1.f / r;
      float hx = rx*inv, hy = ry*inv, hz = rz*inv;
      float fc = (r < 5.f) ? (0.5f * (__cosf(r * 0.6283185307179586f) + 1.f)) : 0.f;
      #pragma unroll
      for (int nn = 0; nn < NMX; nn++){
        float d = r - (5.f/9.f) * (float)nn;
        Rl[tid][nn] = __expf(-2.f * d * d) * fc;
      }
      Yl[tid][0] = 0.28209479177387814f;
      Yl[tid][1] = 0.4886025119029199f * hy;
      Yl[tid][2] = 0.4886025119029199f * hz;
      Yl[tid][3] = 0.4886025119029199f * hx;
      Yl[tid][4] = 1.0925484305920792f * hx * hy;
      Yl[tid][5] = 1.0925484305920792f * hy * hz;
      Yl[tid][6] = 0.31539156525252005f * (3.f * hz * hz - 1.f);
      Yl[tid][7] = 1.0925484305920792f * hx * hz;
      Yl[tid][8] = 0.5462742152960396f * (hx * hx - hy * hy);
    }
    __syncthreads();
    if (nk < 90){
      int lo2 = max(aS, base), hi2 = min(aE, base + nch);
      for (int e = lo2; e < hi2; e++){
        int j = e - base;
        acc += Rl[j][n] * Yl[j][k];
      }
    }
    __syncthreads();
  }
  if (nk < 90) csr[sp * 90 + nk] = acc;
  __syncthreads();
  if (tid < 360){
    int a = tid / 90, nq = tid % 90;
    cl[tid] = ul[a*4+0]*csr[nq] + ul[a*4+1]*csr[90+nq]
            + ul[a*4+2]*csr[180+nq] + ul[a*4+3]*csr[270+nq];
  }
  __syncthreads();
  float s1 = 0.f, s2 = 0.f;
  // pair-major ps: thread t < 104 handles pairs m = 8t..8t+7, all 3 l's.
  if (tid < 104){
    unsigned short ob[24];
    int qc = -1;
    float cq0=0,cq1=0,cq2=0,cq3=0,cq4=0,cq5=0,cq6=0,cq7=0,cq8=0;
    #pragma unroll
    for (int j = 0; j < 8; j++){
      int m = tid * 8 + j;
      float v0 = 0.f, v1 = 0.f, v2 = 0.f, wgt = 0.f;
      if (m < NPAIR){
        int q = qp[m] >> 8, p = qp[m] & 255;
        if (q != qc){
          const float* c = &cl[q * 9];
          cq0=c[0]; cq1=c[1]; cq2=c[2]; cq3=c[3]; cq4=c[4];
          cq5=c[5]; cq6=c[6]; cq7=c[7]; cq8=c[8];
          qc = q;
        }
        const float* cp = &cl[p * 9];
        v0 = cq0 * cp[0];
        v1 = (cq1*cp[1] + cq2*cp[2] + cq3*cp[3]) * 0.5773502691896258f;
        v2 = (cq4*cp[4] + cq5*cp[5] + cq6*cp[6] + cq7*cp[7] + cq8*cp[8]) * 0.4472135954999579f;
        wgt = (p != q) ? 2.f : 1.f;
      }
      ob[j*3+0] = f2bf(v0);
      ob[j*3+1] = f2bf(v1);
      ob[j*3+2] = f2bf(v2);
      s1 += wgt * (v0 + v1 + v2);
      s2 += wgt * (v0*v0 + v1*v1 + v2*v2);
    }
    unsigned short* dst = ps + (size_t)atom * FR + tid * 24;
    *reinterpret_cast<u16x8*>(dst)      = *(const u16x8*)&ob[0];
    *reinterpret_cast<u16x8*>(dst + 8)  = *(const u16x8*)&ob[8];
    *reinterpret_cast<u16x8*>(dst + 16) = *(const u16x8*)&ob[16];
  }
  #pragma unroll
  for (int m = 32; m; m >>= 1){ s1 += __shfl_xor(s1, m, 64); s2 += __shfl_xor(s2, m, 64); }
  int w = tid >> 6, lane = tid & 63;
  if (lane == 0){ red[w] = s1; red[8 + w] = s2; }
  __syncthreads();
  if (tid == 0){
    float t1 = red[0] + red[1];
    float t2 = red[8] + red[9];
    float mean = t1 * (1.f / FF);
    float var = t2 * (1.f / FF) - mean * mean;
    var = fmaxf(var, 0.f);
    stats[2*atom]   = mean;
    stats[2*atom+1] = rsqrtf(var + 1e-5f);
  }
}

// ---------------- weight prep v2: single pass over W1, all 4 species -----------------
// Wg[s][n][f'=3m+l] = gamma[fa]*Wmix + (p!=q) gamma[fb]*Wmix_b, Wmix = sum_a U[a,s]W1[a]
// grid (8 nblk, 26 pairblk), 256 thr: (pl = tid>>6) parallel (pair,l) combos, nn = tid&63
__global__ __launch_bounds__(256) void k_wg2(
    const float* __restrict__ W1, const float* __restrict__ U,
    const float* __restrict__ gamma, const float* __restrict__ beta,
    unsigned short* __restrict__ Wg, float* __restrict__ gW, float* __restrict__ bW)
{
  __shared__ unsigned short og[4][64][96];
  __shared__ unsigned short qp[NPAIR];
  int n0 = blockIdx.x * 64, m0 = blockIdx.y * 32;
  int tid = threadIdx.x, pl = tid >> 6, nn = tid & 63;
  build_qp(qp, tid);
  float u[4][4]; // [a][s]
  #pragma unroll
  for (int a = 0; a < 4; a++)
    #pragma unroll
    for (int s = 0; s < 4; s++) u[a][s] = U[a*4 + s];
  __syncthreads();
  float gs[4] = {0,0,0,0}, bs[4] = {0,0,0,0};
  for (int it = 0; it < 24; it++){
    int plc = it * 4 + pl;            // 0..95
    int m = m0 + plc / 3, l = plc % 3;
    float tg[4] = {0,0,0,0}, tb[4] = {0,0,0,0};
    if (m < NPAIR){
      int q = qp[m] >> 8, p = qp[m] & 255;
      int fa = (q * 40 + p) * 3 + l;
      float ga = gamma[fa], ba = beta[fa];
      float gb = 0.f, bb = 0.f;
      int fb = fa;
      if (p != q){ fb = (p * 40 + q) * 3 + l; gb = gamma[fb]; bb = beta[fb]; }
      #pragma unroll
      for (int a = 0; a < 4; a++){
        float wa = W1[(size_t)a * FF * 512 + (size_t)fa * 512 + n0 + nn];
        float wb = (p != q) ? W1[(size_t)a * FF * 512 + (size_t)fb * 512 + n0 + nn] : 0.f;
        float gf = ga * wa + gb * wb;
        float bf = ba * wa + bb * wb;
        #pragma unroll
        for (int s = 0; s < 4; s++){
          tg[s] += u[a][s] * gf;
          tb[s] += u[a][s] * bf;
        }
      }
    }
    #pragma unroll
    for (int s = 0; s < 4; s++){
      og[s][nn][plc] = f2bf(tg[s]);
      gs[s] += tg[s];
      bs[s] += tb[s];
    }
  }
  #pragma unroll
  for (int s = 0; s < 4; s++){
    atomic_add_f(&gW[s * 512 + n0 + nn], gs[s]);
    atomic_add_f(&bW[s * 512 + n0 + nn], bs[s]);
  }
  __syncthreads();
  for (int idx = tid; idx < 4 * 64 * 12; idx += 256){
    int c8 = idx % 12; int sn = idx / 12; int s = sn >> 6, nnn = sn & 63;
    u16x8 v = *reinterpret_cast<const u16x8*>(&og[s][nnn][c8 * 8]);
    *reinterpret_cast<u16x8*>(&Wg[((size_t)s * 512 + n0 + nnn) * FR + 3 * m0 + c8 * 8]) = v;
  }
}

__global__ __launch_bounds__(256) void k_w2t(
    const float* __restrict__ W2, const float* __restrict__ U,
    unsigned short* __restrict__ W2t)
{
  __shared__ float t[64][65];
  int n0 = blockIdx.x * 64, k0 = blockIdx.y * 64, s = blockIdx.z;
  float u0 = U[s], u1 = U[4+s], u2 = U[8+s], u3 = U[12+s];
  int tid = threadIdx.x;
  #pragma unroll 4
  for (int rep = 0; rep < 16; rep++){
    int idx = rep * 256 + tid;
    int ki = idx >> 6, ni = idx & 63;
    size_t base = (size_t)(k0 + ki) * 512 + (n0 + ni);
    t[ki][ni] = u0*W2[base] + u1*W2[base + 512*512]
              + u2*W2[base + 2*512*512] + u3*W2[base + 3*512*512];
  }
  __syncthreads();
  #pragma unroll 4
  for (int rep = 0; rep < 16; rep++){
    int idx = rep * 256 + tid;
    int ni = idx >> 6, ki = idx & 63;
    W2t[((size_t)s * 512 + n0 + ni) * 512 + k0 + ki] = f2bf(t[ki][ni]);
  }
}

__global__ void k_w3(const float* __restrict__ W3, const float* __restrict__ U,
                     float* __restrict__ W3s)
{
  int idx = blockIdx.x * 256 + threadIdx.x;
  if (idx < 4 * 512){
    int s = idx >> 9, k = idx & 511;
    W3s[idx] = U[s]*W3[k] + U[4+s]*W3[512+k] + U[8+s]*W3[2*512+k] + U[12+s]*W3[3*512+k];
  }
}

// ---------------- GEMM template (128x128 tile, BK=64, bf16 MFMA) ----------------
template<int EPI, int NSPLIT>
__global__ __launch_bounds__(256) void k_gemm(
    const unsigned short* __restrict__ Ag, int lda, int K,
    const unsigned short* __restrict__ Btg,
    const int* __restrict__ list, const int* __restrict__ offs, const int* __restrict__ cnt,
    unsigned short* __restrict__ pout,
    const float* __restrict__ W3s, float* __restrict__ pacc)
{
  __shared__ alignas(16) char smem[32768];
  const int NV = 4 * NSPLIT;
  int b = blockIdx.x;
  int y = (b & 7) + 8 * (b / (8 * NV));
  int v = (b >> 3) % NV;
  int x = v & 3, kh = v >> 2;

  int s = 0, t = y;
  for (; s < 4; s++){
    int nts = (cnt[s] + 127) >> 7;
    if (t < nts) break;
    t -= nts;
  }
  if (s >= 4) return;
  int cntS = cnt[s], offS = offs[s];
  int rt = t, n0 = x * 128;
  int tid = threadIdx.x, w = tid >> 6, lane = tid & 63;
  int wr = w >> 1, wc = w & 1;

  const unsigned short* Bts = Btg + (size_t)s * 512 * K;
  const unsigned short* gA[4];
  const unsigned short* gB[4];
  char* lA[4];
  char* lB[4];
  #pragma unroll
  for (int it = 0; it < 4; it++){
    int g = it * 4 + w;
    int idx = g * 64 + lane;
    int row = idx >> 3, ch = idx & 7;
    int cg = ch ^ (row & 7);
    int gr = rt * 128 + row; gr = gr < cntS ? gr : cntS - 1;
    int atom = list[offS + gr];
    gA[it] = Ag + (size_t)atom * lda + cg * 8;
    lA[it] = smem + g * 1024;
    gB[it] = Bts + (size_t)(n0 + row) * K + cg * 8;
    lB[it] = smem + 16384 + g * 1024;
  }

  int hi = lane >> 4, lo = lane & 15;
  f32x4 acc[4][4];
  #pragma unroll
  for (int mi = 0; mi < 4; mi++)
    #pragma unroll
    for (int ni = 0; ni < 4; ni++)
      #pragma unroll
      for (int r = 0; r < 4; r++) acc[mi][ni][r] = 0.f;

  int abase[4], a7[4], bbase[4], b7[4];
  #pragma unroll
  for (int mi = 0; mi < 4; mi++){ int row = wr*64 + mi*16 + lo; abase[mi] = row*128; a7[mi] = row & 7; }
  #pragma unroll
  for (int ni = 0; ni < 4; ni++){ int row = wc*64 + ni*16 + lo; bbase[ni] = 16384 + row*128; b7[ni] = row & 7; }

  int nk = K / 64;
  int k0 = ((nk * kh) / NSPLIT) * 64;
  int k1 = ((nk * (kh + 1)) / NSPLIT) * 64;

  for (int kt = k0; kt < k1; kt += 64){
    #pragma unroll
    for (int it = 0; it < 4; it++) gload16(gA[it] + kt, lA[it]);
    #pragma unroll
    for (int it = 0; it < 4; it++) gload16(gB[it] + kt, lB[it]);
    __syncthreads();
    #pragma unroll
    for (int kk = 0; kk < 2; kk++){
      bf16x8 af[4], bfr[4];
      #pragma unroll
      for (int mi = 0; mi < 4; mi++)
        af[mi] = *(const bf16x8*)(smem + abase[mi] + (((kk*4 + hi) ^ a7[mi]) << 4));
      #pragma unroll
      for (int ni = 0; ni < 4; ni++)
        bfr[ni] = *(const bf16x8*)(smem + bbase[ni] + (((kk*4 + hi) ^ b7[ni]) << 4));
      #pragma unroll
      for (int mi = 0; mi < 4; mi++)
        #pragma unroll
        for (int ni = 0; ni < 4; ni++)
          acc[mi][ni] = __builtin_amdgcn_mfma_f32_16x16x32_bf16(af[mi], bfr[ni], acc[mi][ni], 0, 0, 0);
    }
    __syncthreads();
  }

  int gn[4];
  #pragma unroll
  for (int ni = 0; ni < 4; ni++) gn[ni] = n0 + wc*64 + ni*16 + lo;

  if (EPI == 0){
    #pragma unroll
    for (int mi = 0; mi < 4; mi++){
      #pragma unroll
      for (int j = 0; j < 4; j++){
        int gr = rt*128 + wr*64 + mi*16 + hi*4 + j;
        if (gr < cntS){
          int atom = list[offS + gr];
          #pragma unroll
          for (int ni = 0; ni < 4; ni++)
            pout[((size_t)kh * NA + atom) * 512 + gn[ni]] = f2bf(acc[mi][ni][j]);
        }
      }
    }
  } else {
    float w3v[4];
    #pragma unroll
    for (int ni = 0; ni < 4; ni++) w3v[ni] = W3s[s * 512 + gn[ni]];
    float* pslot = pacc + (size_t)(x * 2 + wc) * NA;
    #pragma unroll
    for (int mi = 0; mi < 4; mi++){
      #pragma unroll
      for (int j = 0; j < 4; j++){
        int gr = rt*128 + wr*64 + mi*16 + hi*4 + j;
        if (gr < cntS){
          int atom = list[offS + gr];
          float pdot = 0.f;
          #pragma unroll
          for (int ni = 0; ni < 4; ni++)
            pdot += silu(acc[mi][ni][j]) * w3v[ni];
          pdot += __shfl_xor(pdot, 1, 16);
          pdot += __shfl_xor(pdot, 2, 16);
          pdot += __shfl_xor(pdot, 4, 16);
          pdot += __shfl_xor(pdot, 8, 16);
          if (lo == 0) pslot[atom] = pdot;
        }
      }
    }
  }
}

// ---------------- epilogue: combine split-K partials + LN-affine + silu -> h1 ---------
__global__ __launch_bounds__(256) void k_epi(
    const unsigned short* __restrict__ pbuf, const float* __restrict__ stats,
    const float* __restrict__ gW, const float* __restrict__ bW,
    const int* __restrict__ numbers, unsigned short* __restrict__ h1)
{
  int w = threadIdx.x >> 6, lane = threadIdx.x & 63;
  int atom = blockIdx.x * 4 + w;
  int s = numbers[atom];
  float mean = stats[2*atom], rstd = stats[2*atom+1];
  int c0 = lane * 8;
  u16x8 a0 = *reinterpret_cast<const u16x8*>(pbuf + (size_t)atom * 512 + c0);
  u16x8 a1 = *reinterpret_cast<const u16x8*>(pbuf + (size_t)(NA + atom) * 512 + c0);
  unsigned short o[8];
  #pragma unroll
  for (int j = 0; j < 8; j++){
    int c = c0 + j;
    float acc = bf2f(a0[j]) + bf2f(a1[j]);
    float vv = rstd * acc + bW[s*512 + c] - mean * rstd * gW[s*512 + c];
    o[j] = f2bf(silu(vv));
  }
  *reinterpret_cast<u16x8*>(h1 + (size_t)atom * 512 + c0) = *(const u16x8*)o;
}

// ---------------- final: sum 8 pacc partials/atom, wave-uniform molecule atomic -------
__global__ __launch_bounds__(256) void k_final2(
    const float* __restrict__ pacc, const int* __restrict__ numbers,
    const int* __restrict__ batch, const float* __restrict__ Wc,
    float* __restrict__ molOut)
{
  int atom = blockIdx.x * 256 + threadIdx.x;
  int lane = threadIdx.x & 63;
  float sum = 0.f;
  #pragma unroll
  for (int p = 0; p < 8; p++) sum += pacc[(size_t)p * NA + atom];
  float val = sum * (1.f / 128.f) + Wc[numbers[atom]];
  int mol = batch[atom];
  int m0 = __shfl(mol, 0, 64);
  int m63 = __shfl(mol, 63, 64);
  if (m0 == m63){
    #pragma unroll
    for (int m = 32; m; m >>= 1) val += __shfl_xor(val, m, 64);
    if (lane == 0) atomic_add_f(&molOut[mol], val);
  } else {
    atomic_add_f(&molOut[mol], val);
  }
}

extern "C" void kernel_launch(void* const* d_in, const int* in_sizes, int n_in,
                              void* d_out, int out_size, void* d_ws, size_t ws_size,
                              hipStream_t stream)
{
  const float* pos     = (const float*)d_in[0];
  const float* cells   = (const float*)d_in[1];
  const int*   numbers = (const int*)d_in[2];
  const int*   ei      = (const int*)d_in[3];
  const float* eoff    = (const float*)d_in[4];
  const int*   batch   = (const int*)d_in[5];
  const float* U       = (const float*)d_in[6];
  const float* gamma   = (const float*)d_in[7];
  const float* beta    = (const float*)d_in[8];
  const float* W1      = (const float*)d_in[9];
  const float* W2      = (const float*)d_in[10];
  const float* W3      = (const float*)d_in[11];
  const float* Wc      = (const float*)d_in[12];
  float* out = (float*)d_out;

  char* ws = (char*)d_ws;
  size_t off = 0;
  auto alloc = [&](size_t bytes) -> void* {
    void* p = ws + off;
    off += (bytes + 255) & ~(size_t)255;
    return p;
  };
  unsigned short* ps   = (unsigned short*)alloc((size_t)NA * FR * 2);      // 78 MB
  unsigned short* pbuf = (unsigned short*)alloc((size_t)2 * NA * 512 * 2); // 32 MB
  float* stats         = (float*)alloc((size_t)NA * 2 * 4);
  unsigned short* Wg1  = (unsigned short*)alloc((size_t)4 * 512 * FR * 2); // 10.2 MB
  float* gW            = (float*)alloc(4 * 512 * 4);
  float* bW            = (float*)alloc(4 * 512 * 4);
  unsigned short* W2t  = (unsigned short*)alloc((size_t)4 * 512 * 512 * 2);
  float* W3s           = (float*)alloc(4 * 512 * 4);
  unsigned short* h1   = (unsigned short*)alloc((size_t)NA * 512 * 2);
  float* pacc          = (float*)alloc((size_t)8 * NA * 4);
  int* list            = (int*)alloc(NA * 4);
  int* perm            = (int*)alloc((size_t)NE * 4);
  int* startsK         = (int*)alloc((65536 + 1) * 4);
  int* cnt64k          = (int*)alloc(65536 * 4);
  int* cursor64k       = (int*)alloc(65536 * 4);
  int* bsum            = (int*)alloc(256 * 4);
  int* boff            = (int*)alloc(256 * 4);
  int* bhist           = (int*)alloc(64 * 4 * 4);
  int* boffs           = (int*)alloc(64 * 4 * 4);
  int* ints            = (int*)alloc(64);
  int* cnt = ints; int* offs = ints + 8;

  hipMemsetAsync(cnt64k, 0, 65536 * 4, stream);
  hipMemsetAsync(gW, 0, 4 * 512 * 4, stream);
  hipMemsetAsync(bW, 0, 4 * 512 * 4, stream);
  hipMemsetAsync(out, 0, (size_t)out_size * 4, stream);

  // edge counting sort by (recv, sender-species)
  k_hist<<<NE / 256, 256, 0, stream>>>(ei, numbers, cnt64k);
  k_scanA<<<256, 256, 0, stream>>>(cnt64k, bsum);
  k_scanB<<<1, 256, 0, stream>>>(bsum, boff, startsK);
  k_scanC<<<256, 256, 0, stream>>>(cnt64k, boff, startsK, cursor64k);
  k_sortperm<<<NE / 256, 256, 0, stream>>>(ei, numbers, cursor64k, perm);

  // atom species grouping: contention-free stable counting sort
  k_acount<<<NA / 256, 256, 0, stream>>>(numbers, bhist);
  k_aoffs<<<1, 64, 0, stream>>>(bhist, boffs, ints);
  k_aplace<<<NA / 256, 256, 0, stream>>>(numbers, boffs, list);

  // fused per-atom pipeline (512 threads, species-uniform waves, pair-major ps)
  k_atom3<<<NA, 512, 0, stream>>>(pos, cells, ei, eoff, batch, startsK, perm, U, ps, stats);

  // weight prep (single-pass folded W1; W2 mix; W3 mix)
  k_wg2<<<dim3(8, 26), 256, 0, stream>>>(W1, U, gamma, beta, Wg1, gW, bW);
  k_w2t<<<dim3(8, 8, 4), 256, 0, stream>>>(W2, U, W2t);
  k_w3<<<8, 256, 0, stream>>>(W3, U, W3s);

  // GEMM1 split-K=2 (K=2496), then LN+silu epilogue
  k_gemm<0, 2><<<1088, 256, 0, stream>>>(ps, FR, FR, Wg1, list, offs, cnt,
                                         pbuf, nullptr, nullptr);
  k_epi<<<NA / 4, 256, 0, stream>>>(pbuf, stats, gW, bW, numbers, h1);

  // GEMM2 with fused silu + W3 dot -> per-atom partials (atomic-free)
  k_gemm<2, 1><<<544, 256, 0, stream>>>(h1, 512, 512, W2t, list, offs, cnt,
                                        nullptr, W3s, pacc);
  k_final2<<<NA / 256, 256, 0, stream>>>(pacc, numbers, batch, Wc, out);
}

// Round 13
// 331.413 us; speedup vs baseline: 1.0938x; 1.0825x over previous
//
#include <hip/hip_runtime.h>

#define NA   16384
#define NE   524288
#define NM   256
#define FF   4800
#define FR   2688   // folded K: 55 pair-blocks * 48 + 48 pad ; f' = b*48 + l*16 + qi*4 + pi
#define HH   512
#define NMX  10
#define NSPH 9

typedef __bf16 bf16x8 __attribute__((ext_vector_type(8)));
typedef float  f32x4  __attribute__((ext_vector_type(4)));
typedef unsigned short u16x8 __attribute__((ext_vector_type(8)));

__device__ inline unsigned short f2bf(float x){
  unsigned int u = __builtin_bit_cast(unsigned int, x);
  u += 0x7fffu + ((u >> 16) & 1u);
  return (unsigned short)(u >> 16);
}
__device__ inline float bf2f(unsigned short h){
  unsigned int u = ((unsigned int)h) << 16;
  return __builtin_bit_cast(float, u);
}
__device__ inline void atomic_add_f(float* p, float v){
  __hip_atomic_fetch_add(p, v, __ATOMIC_RELAXED, __HIP_MEMORY_SCOPE_AGENT);
}
__device__ inline void gload16(const void* g, void* l){
  __builtin_amdgcn_global_load_lds(
      (const __attribute__((address_space(1))) unsigned int*)g,
      (__attribute__((address_space(3))) unsigned int*)l, 16, 0, 0);
}
__device__ inline float silu(float x){ return x / (1.f + __expf(-x)); }

// decode pair-block b (0..54) -> (qb, pb), qb <= pb < 10
__device__ inline void decode_blk(int b, int& qb, int& pb){
  int q = 0, rem = b;
  while (rem >= 10 - q){ rem -= 10 - q; q++; }
  qb = q; pb = q + rem;
}

// compute one 4x4 pair block for one l (CNT components), static indexing only
template<int CNT>
__device__ inline void ps_block(const float* __restrict__ cl, int qb, int pb, int off,
                                float nrm, bool diag, unsigned short* ob,
                                float& s1, float& s2){
  float cq[4][CNT], cp[4][CNT];
  #pragma unroll
  for (int i = 0; i < 4; i++)
    #pragma unroll
    for (int k = 0; k < CNT; k++){
      cq[i][k] = cl[(qb*4 + i)*9 + off + k];
      cp[i][k] = cl[(pb*4 + i)*9 + off + k];
    }
  #pragma unroll
  for (int qi = 0; qi < 4; qi++)
    #pragma unroll
    for (int pi = 0; pi < 4; pi++){
      float v = 0.f;
      #pragma unroll
      for (int k = 0; k < CNT; k++) v += cq[qi][k] * cp[pi][k];
      v *= nrm;
      float wgt = diag ? ((qi < pi) ? 2.f : ((qi == pi) ? 1.f : 0.f)) : 2.f;
      if (diag && qi > pi) v = 0.f;
      ob[qi*4 + pi] = f2bf(v);
      s1 += wgt * v;
      s2 += wgt * v * v;
    }
}

__device__ inline int block_scan_excl(int v, int tid, int* lds){
  int lane = tid & 63, w = tid >> 6;
  int x = v;
  #pragma unroll
  for (int d = 1; d < 64; d <<= 1){
    int y = __shfl_up(x, d, 64);
    if (lane >= d) x += y;
  }
  if (lane == 63) lds[w] = x;
  __syncthreads();
  int wsum = 0;
  for (int i = 0; i < w; i++) wsum += lds[i];
  return wsum + x - v;
}

// ---------------- edge counting sort by key = recv*4 + species(sender) ----------------
__global__ __launch_bounds__(256) void k_hist(const int* __restrict__ ei,
                                              const int* __restrict__ numbers,
                                              int* __restrict__ cnt64k){
  int e = blockIdx.x * 256 + threadIdx.x;
  if (e < NE){
    int key = ei[NE + e] * 4 + numbers[ei[e]];
    atomicAdd(&cnt64k[key], 1);
  }
}

__global__ __launch_bounds__(256) void k_scanA(const int* __restrict__ cnt64k,
                                               int* __restrict__ bsum){
  __shared__ int lds[4];
  int tid = threadIdx.x;
  int v = cnt64k[blockIdx.x * 256 + tid];
  int lane = tid & 63;
  #pragma unroll
  for (int m = 32; m; m >>= 1) v += __shfl_xor(v, m, 64);
  if (lane == 0) lds[tid >> 6] = v;
  __syncthreads();
  if (tid == 0) bsum[blockIdx.x] = lds[0] + lds[1] + lds[2] + lds[3];
}

__global__ __launch_bounds__(256) void k_scanB(const int* __restrict__ bsum,
                                               int* __restrict__ boff, int* __restrict__ starts){
  __shared__ int lds[4];
  int tid = threadIdx.x;
  int v = bsum[tid];
  int e = block_scan_excl(v, tid, lds);
  boff[tid] = e;
  if (tid == 0) starts[65536] = NE;
}

__global__ __launch_bounds__(256) void k_scanC(const int* __restrict__ cnt64k,
                                               const int* __restrict__ boff,
                                               int* __restrict__ starts, int* __restrict__ cursor){
  __shared__ int lds[4];
  int tid = threadIdx.x;
  int bin = blockIdx.x * 256 + tid;
  int v = cnt64k[bin];
  int e = block_scan_excl(v, tid, lds) + boff[blockIdx.x];
  starts[bin] = e;
  cursor[bin] = e;
}

__global__ __launch_bounds__(256) void k_sortperm(const int* __restrict__ ei,
                                                  const int* __restrict__ numbers,
                                                  int* __restrict__ cursor, int* __restrict__ perm){
  int e = blockIdx.x * 256 + threadIdx.x;
  if (e < NE){
    int key = ei[NE + e] * 4 + numbers[ei[e]];
    int p = atomicAdd(&cursor[key], 1);
    perm[p] = e;
  }
}

// ---------------- species grouping of atoms (contention-free counting sort) -----------
__global__ __launch_bounds__(256) void k_acount(const int* __restrict__ numbers,
                                                int* __restrict__ bhist){
  __shared__ int h[4];
  int tid = threadIdx.x;
  if (tid < 4) h[tid] = 0;
  __syncthreads();
  atomicAdd(&h[numbers[blockIdx.x * 256 + tid]], 1);
  __syncthreads();
  if (tid < 4) bhist[blockIdx.x * 4 + tid] = h[tid];
}

__global__ void k_aoffs(const int* __restrict__ bhist, int* __restrict__ boffs,
                        int* __restrict__ ints){
  if (threadIdx.x == 0){
    int* cnt = ints; int* offs = ints + 8;
    int tot[4] = {0,0,0,0};
    for (int b = 0; b < 64; b++)
      for (int s = 0; s < 4; s++) tot[s] += bhist[b*4 + s];
    int o = 0;
    for (int s = 0; s < 4; s++){ cnt[s] = tot[s]; offs[s] = o; o += tot[s]; }
    offs[4] = o;
    int run[4];
    for (int s = 0; s < 4; s++) run[s] = offs[s];
    for (int b = 0; b < 64; b++)
      for (int s = 0; s < 4; s++){ boffs[b*4 + s] = run[s]; run[s] += bhist[b*4 + s]; }
  }
}

__global__ __launch_bounds__(256) void k_aplace(const int* __restrict__ numbers,
                                                const int* __restrict__ boffs,
                                                int* __restrict__ list){
  __shared__ int ws[4][4];
  int tid = threadIdx.x, w = tid >> 6, lane = tid & 63;
  int i = blockIdx.x * 256 + tid;
  int sp = numbers[i];
  int rank = 0;
  #pragma unroll
  for (int s = 0; s < 4; s++){
    unsigned long long m = __ballot(sp == s);
    if (s == sp) rank = __popcll(m & (((unsigned long long)1 << lane) - 1));
    if (lane == 0) ws[w][s] = __popcll(m);
  }
  __syncthreads();
  int pre = 0;
  for (int w2 = 0; w2 < w; w2++) pre += ws[w2][sp];
  list[boffs[blockIdx.x * 4 + sp] + pre + rank] = i;
}

// ---------------- fused per-atom: edge accum -> U-mix -> 4x4-tiled folded ps + stats --
__global__ __launch_bounds__(384) void k_atom(
    const float* __restrict__ pos, const float* __restrict__ cells,
    const int* __restrict__ ei, const float* __restrict__ eoff,
    const int* __restrict__ batch, const int* __restrict__ startsK,
    const int* __restrict__ perm, const float* __restrict__ U,
    unsigned short* __restrict__ ps, float* __restrict__ stats)
{
  __shared__ float Rl[64][NMX];
  __shared__ float Yl[64][NSPH];
  __shared__ float csr[360];
  __shared__ float cl[360];
  __shared__ float red[16];
  __shared__ float ul[16];
  int atom = blockIdx.x;
  int tid = threadIdx.x;
  if (tid < 16) ul[tid] = U[tid];
  int e0 = startsK[atom * 4], e1 = startsK[atom * 4 + 4];
  float px = pos[atom*3+0], py = pos[atom*3+1], pz = pos[atom*3+2];
  int sp = tid / 90, n = (tid % 90) / 9, k = tid % 9;
  int aS = 0, aE = 0;
  if (tid < 360){ aS = startsK[atom * 4 + sp]; aE = startsK[atom * 4 + sp + 1]; }
  float acc = 0.f;
  for (int base = e0; base < e1; base += 64){
    int nch = min(64, e1 - base);
    if (tid < nch){
      int e = perm[base + tid];
      int snd = ei[e];
      const float* C = cells + (size_t)batch[snd] * 9;
      float o0 = eoff[e*3+0], o1 = eoff[e*3+1], o2 = eoff[e*3+2];
      float rx = px - pos[snd*3+0] + o0*C[0] + o1*C[3] + o2*C[6];
      float ry = py - pos[snd*3+1] + o0*C[1] + o1*C[4] + o2*C[7];
      float rz = pz - pos[snd*3+2] + o0*C[2] + o1*C[5] + o2*C[8];
      float r = sqrtf(rx*rx + ry*ry + rz*rz + 1e-12f);
      float inv = 1.f / r;
      float hx = rx*inv, hy = ry*inv, hz = rz*inv;
      float fc = (r < 5.f) ? (0.5f * (__cosf(r * 0.6283185307179586f) + 1.f)) : 0.f;
      #pragma unroll
      for (int nn = 0; nn < NMX; nn++){
        float d = r - (5.f/9.f) * (float)nn;
        Rl[tid][nn] = __expf(-2.f * d * d) * fc;
      }
      Yl[tid][0] = 0.28209479177387814f;
      Yl[tid][1] = 0.4886025119029199f * hy;
      Yl[tid][2] = 0.4886025119029199f * hz;
      Yl[tid][3] = 0.4886025119029199f * hx;
      Yl[tid][4] = 1.0925484305920792f * hx * hy;
      Yl[tid][5] = 1.0925484305920792f * hy * hz;
      Yl[tid][6] = 0.31539156525252005f * (3.f * hz * hz - 1.f);
      Yl[tid][7] = 1.0925484305920792f * hx * hz;
      Yl[tid][8] = 0.5462742152960396f * (hx * hx - hy * hy);
    }
    __syncthreads();
    if (tid < 360){
      int lo2 = max(aS, base), hi2 = min(aE, base + nch);
      for (int e = lo2; e < hi2; e++){
        int j = e - base;
        acc += Rl[j][n] * Yl[j][k];
      }
    }
    __syncthreads();
  }
  if (tid < 360) csr[tid] = acc;
  __syncthreads();
  if (tid < 360){
    int a = tid / 90, nk = tid % 90;
    cl[tid] = ul[a*4+0]*csr[nk] + ul[a*4+1]*csr[90+nk]
            + ul[a*4+2]*csr[180+nk] + ul[a*4+3]*csr[270+nk];
  }
  __syncthreads();
  float s1 = 0.f, s2 = 0.f;
  // ps: waves 0..2 handle l = wave; lane b < 55 does pair-block b (4x4 pairs, 16 outs)
  int l = tid >> 6, b = tid & 63;
  if (l < 3 && b < 55){
    int qb, pb;
    decode_blk(b, qb, pb);
    bool diag = (qb == pb);
    unsigned short ob[16];
    if (l == 0)      ps_block<1>(cl, qb, pb, 0, 1.f, diag, ob, s1, s2);
    else if (l == 1) ps_block<3>(cl, qb, pb, 1, 0.5773502691896258f, diag, ob, s1, s2);
    else             ps_block<5>(cl, qb, pb, 4, 0.4472135954999579f, diag, ob, s1, s2);
    unsigned short* dst = ps + (size_t)atom * FR + b * 48 + l * 16;
    *reinterpret_cast<u16x8*>(dst)     = *(const u16x8*)&ob[0];
    *reinterpret_cast<u16x8*>(dst + 8) = *(const u16x8*)&ob[8];
  } else if (tid >= 192 && tid < 198){
    unsigned short zb[8] = {0,0,0,0,0,0,0,0};
    *reinterpret_cast<u16x8*>(ps + (size_t)atom * FR + 2640 + (tid - 192) * 8) = *(const u16x8*)zb;
  }
  #pragma unroll
  for (int m = 32; m; m >>= 1){ s1 += __shfl_xor(s1, m, 64); s2 += __shfl_xor(s2, m, 64); }
  int w = tid >> 6, lane = tid & 63;
  if (lane == 0){ red[w] = s1; red[8 + w] = s2; }
  __syncthreads();
  if (tid == 0){
    float t1 = 0.f, t2 = 0.f;
    for (int i = 0; i < 6; i++){ t1 += red[i]; t2 += red[8 + i]; }
    float mean = t1 * (1.f / FF);
    float var = t2 * (1.f / FF) - mean * mean;
    var = fmaxf(var, 0.f);
    stats[2*atom]   = mean;
    stats[2*atom+1] = rsqrtf(var + 1e-5f);
  }
}

// ---------------- weight prep: Wg[s][n][f'], f' = b*48 + l*16 + qi*4 + pi -------------
__global__ __launch_bounds__(256) void k_wg1(
    const float* __restrict__ W1, const float* __restrict__ U,
    const float* __restrict__ gamma, const float* __restrict__ beta,
    unsigned short* __restrict__ Wg, float* __restrict__ gW, float* __restrict__ bW)
{
  __shared__ float tg[64][65];
  __shared__ float tb[64][65];
  int n0 = blockIdx.x * 64, f0 = blockIdx.y * 64, s = blockIdx.z;
  float u0 = U[s], u1 = U[4+s], u2 = U[8+s], u3 = U[12+s];
  int tid = threadIdx.x;
  #pragma unroll 4
  for (int rep = 0; rep < 16; rep++){
    int idx = rep * 256 + tid;
    int fi = idx >> 6, ni = idx & 63;
    int fp = f0 + fi;
    int b = fp / 48, r = fp % 48;
    int l = r >> 4, qi = (r >> 2) & 3, pi = r & 3;
    float tgv = 0.f, tbv = 0.f;
    if (b < 55){
      int qb, pb;
      decode_blk(b, qb, pb);
      bool zero = (qb == pb) && (qi > pi);
      if (!zero){
        int q = qb*4 + qi, p = pb*4 + pi;
        int fa = (q * 40 + p) * 3 + l;
        size_t basea = (size_t)fa * 512 + (n0 + ni);
        float wa = u0*W1[basea] + u1*W1[basea + (size_t)FF*512]
                 + u2*W1[basea + (size_t)2*FF*512] + u3*W1[basea + (size_t)3*FF*512];
        tgv = gamma[fa] * wa;
        tbv = beta[fa] * wa;
        if (p != q){
          int fb = (p * 40 + q) * 3 + l;
          size_t baseb = (size_t)fb * 512 + (n0 + ni);
          float wb = u0*W1[baseb] + u1*W1[baseb + (size_t)FF*512]
                   + u2*W1[baseb + (size_t)2*FF*512] + u3*W1[baseb + (size_t)3*FF*512];
          tgv += gamma[fb] * wb;
          tbv += beta[fb] * wb;
        }
      }
    }
    tg[fi][ni] = tgv;
    tb[fi][ni] = tbv;
  }
  __syncthreads();
  #pragma unroll 4
  for (int rep = 0; rep < 16; rep++){
    int idx = rep * 256 + tid;
    int ni = idx >> 6, fi = idx & 63;
    Wg[((size_t)s * 512 + n0 + ni) * FR + f0 + fi] = f2bf(tg[fi][ni]);
  }
  if (tid < 64){
    float sg = 0.f, sb = 0.f;
    for (int fi = 0; fi < 64; fi++){ sg += tg[fi][tid]; sb += tb[fi][tid]; }
    atomic_add_f(&gW[s * 512 + n0 + tid], sg);
    atomic_add_f(&bW[s * 512 + n0 + tid], sb);
  }
}

__global__ __launch_bounds__(256) void k_w2t(
    const float* __restrict__ W2, const float* __restrict__ U,
    unsigned short* __restrict__ W2t)
{
  __shared__ float t[64][65];
  int n0 = blockIdx.x * 64, k0 = blockIdx.y * 64, s = blockIdx.z;
  float u0 = U[s], u1 = U[4+s], u2 = U[8+s], u3 = U[12+s];
  int tid = threadIdx.x;
  #pragma unroll 4
  for (int rep = 0; rep < 16; rep++){
    int idx = rep * 256 + tid;
    int ki = idx >> 6, ni = idx & 63;
    size_t base = (size_t)(k0 + ki) * 512 + (n0 + ni);
    t[ki][ni] = u0*W2[base] + u1*W2[base + 512*512]
              + u2*W2[base + 2*512*512] + u3*W2[base + 3*512*512];
  }
  __syncthreads();
  #pragma unroll 4
  for (int rep = 0; rep < 16; rep++){
    int idx = rep * 256 + tid;
    int ni = idx >> 6, ki = idx & 63;
    W2t[((size_t)s * 512 + n0 + ni) * 512 + k0 + ki] = f2bf(t[ki][ni]);
  }
}

__global__ void k_w3(const float* __restrict__ W3, const float* __restrict__ U,
                     float* __restrict__ W3s)
{
  int idx = blockIdx.x * 256 + threadIdx.x;
  if (idx < 4 * 512){
    int s = idx >> 9, k = idx & 511;
    W3s[idx] = U[s]*W3[k] + U[4+s]*W3[512+k] + U[8+s]*W3[2*512+k] + U[12+s]*W3[3*512+k];
  }
}

// ---------------- GEMM template (128x128 tile, BK=64, bf16 MFMA) ----------------
template<int EPI, int NSPLIT>
__global__ __launch_bounds__(256) void k_gemm(
    const unsigned short* __restrict__ Ag, int lda, int K,
    const unsigned short* __restrict__ Btg,
    const int* __restrict__ list, const int* __restrict__ offs, const int* __restrict__ cnt,
    unsigned short* __restrict__ pout,
    const float* __restrict__ W3s, float* __restrict__ pacc)
{
  __shared__ alignas(16) char smem[32768];
  const int NV = 4 * NSPLIT;
  int b = blockIdx.x;
  int y = (b & 7) + 8 * (b / (8 * NV));
  int v = (b >> 3) % NV;
  int x = v & 3, kh = v >> 2;

  int s = 0, t = y;
  for (; s < 4; s++){
    int nts = (cnt[s] + 127) >> 7;
    if (t < nts) break;
    t -= nts;
  }
  if (s >= 4) return;
  int cntS = cnt[s], offS = offs[s];
  int rt = t, n0 = x * 128;
  int tid = threadIdx.x, w = tid >> 6, lane = tid & 63;
  int wr = w >> 1, wc = w & 1;

  const unsigned short* Bts = Btg + (size_t)s * 512 * K;
  const unsigned short* gA[4];
  const unsigned short* gB[4];
  char* lA[4];
  char* lB[4];
  #pragma unroll
  for (int it = 0; it < 4; it++){
    int g = it * 4 + w;
    int idx = g * 64 + lane;
    int row = idx >> 3, ch = idx & 7;
    int cg = ch ^ (row & 7);
    int gr = rt * 128 + row; gr = gr < cntS ? gr : cntS - 1;
    int atom = list[offS + gr];
    gA[it] = Ag + (size_t)atom * lda + cg * 8;
    lA[it] = smem + g * 1024;
    gB[it] = Bts + (size_t)(n0 + row) * K + cg * 8;
    lB[it] = smem + 16384 + g * 1024;
  }

  int hi = lane >> 4, lo = lane & 15;
  f32x4 acc[4][4];
  #pragma unroll
  for (int mi = 0; mi < 4; mi++)
    #pragma unroll
    for (int ni = 0; ni < 4; ni++)
      #pragma unroll
      for (int r = 0; r < 4; r++) acc[mi][ni][r] = 0.f;

  int abase[4], a7[4], bbase[4], b7[4];
  #pragma unroll
  for (int mi = 0; mi < 4; mi++){ int row = wr*64 + mi*16 + lo; abase[mi] = row*128; a7[mi] = row & 7; }
  #pragma unroll
  for (int ni = 0; ni < 4; ni++){ int row = wc*64 + ni*16 + lo; bbase[ni] = 16384 + row*128; b7[ni] = row & 7; }

  int nk = K / 64;
  int k0 = ((nk * kh) / NSPLIT) * 64;
  int k1 = ((nk * (kh + 1)) / NSPLIT) * 64;

  for (int kt = k0; kt < k1; kt += 64){
    #pragma unroll
    for (int it = 0; it < 4; it++) gload16(gA[it] + kt, lA[it]);
    #pragma unroll
    for (int it = 0; it < 4; it++) gload16(gB[it] + kt, lB[it]);
    __syncthreads();
    #pragma unroll
    for (int kk = 0; kk < 2; kk++){
      bf16x8 af[4], bfr[4];
      #pragma unroll
      for (int mi = 0; mi < 4; mi++)
        af[mi] = *(const bf16x8*)(smem + abase[mi] + (((kk*4 + hi) ^ a7[mi]) << 4));
      #pragma unroll
      for (int ni = 0; ni < 4; ni++)
        bfr[ni] = *(const bf16x8*)(smem + bbase[ni] + (((kk*4 + hi) ^ b7[ni]) << 4));
      #pragma unroll
      for (int mi = 0; mi < 4; mi++)
        #pragma unroll
        for (int ni = 0; ni < 4; ni++)
          acc[mi][ni] = __builtin_amdgcn_mfma_f32_16x16x32_bf16(af[mi], bfr[ni], acc[mi][ni], 0, 0, 0);
    }
    __syncthreads();
  }

  int gn[4];
  #pragma unroll
  for (int ni = 0; ni < 4; ni++) gn[ni] = n0 + wc*64 + ni*16 + lo;

  if (EPI == 0){
    #pragma unroll
    for (int mi = 0; mi < 4; mi++){
      #pragma unroll
      for (int j = 0; j < 4; j++){
        int gr = rt*128 + wr*64 + mi*16 + hi*4 + j;
        if (gr < cntS){
          int atom = list[offS + gr];
          #pragma unroll
          for (int ni = 0; ni < 4; ni++)
            pout[((size_t)kh * NA + atom) * 512 + gn[ni]] = f2bf(acc[mi][ni][j]);
        }
      }
    }
  } else {
    float w3v[4];
    #pragma unroll
    for (int ni = 0; ni < 4; ni++) w3v[ni] = W3s[s * 512 + gn[ni]];
    float* pslot = pacc + (size_t)(x * 2 + wc) * NA;
    #pragma unroll
    for (int mi = 0; mi < 4; mi++){
      #pragma unroll
      for (int j = 0; j < 4; j++){
        int gr = rt*128 + wr*64 + mi*16 + hi*4 + j;
        if (gr < cntS){
          int atom = list[offS + gr];
          float pdot = 0.f;
          #pragma unroll
          for (int ni = 0; ni < 4; ni++)
            pdot += silu(acc[mi][ni][j]) * w3v[ni];
          pdot += __shfl_xor(pdot, 1, 16);
          pdot += __shfl_xor(pdot, 2, 16);
          pdot += __shfl_xor(pdot, 4, 16);
          pdot += __shfl_xor(pdot, 8, 16);
          if (lo == 0) pslot[atom] = pdot;
        }
      }
    }
  }
}

// ---------------- epilogue: combine split-K partials + LN-affine + silu -> h1 ---------
__global__ __launch_bounds__(256) void k_epi(
    const unsigned short* __restrict__ pbuf, const float* __restrict__ stats,
    const float* __restrict__ gW, const float* __restrict__ bW,
    const int* __restrict__ numbers, unsigned short* __restrict__ h1)
{
  int w = threadIdx.x >> 6, lane = threadIdx.x & 63;
  int atom = blockIdx.x * 4 + w;
  int s = numbers[atom];
  float mean = stats[2*atom], rstd = stats[2*atom+1];
  int c0 = lane * 8;
  u16x8 a0 = *reinterpret_cast<const u16x8*>(pbuf + (size_t)atom * 512 + c0);
  u16x8 a1 = *reinterpret_cast<const u16x8*>(pbuf + (size_t)(NA + atom) * 512 + c0);
  unsigned short o[8];
  #pragma unroll
  for (int j = 0; j < 8; j++){
    int c = c0 + j;
    float acc = bf2f(a0[j]) + bf2f(a1[j]);
    float vv = rstd * acc + bW[s*512 + c] - mean * rstd * gW[s*512 + c];
    o[j] = f2bf(silu(vv));
  }
  *reinterpret_cast<u16x8*>(h1 + (size_t)atom * 512 + c0) = *(const u16x8*)o;
}

// ---------------- final: sum 8 pacc partials/atom, wave-uniform molecule atomic -------
__global__ __launch_bounds__(256) void k_final2(
    const float* __restrict__ pacc, const int* __restrict__ numbers,
    const int* __restrict__ batch, const float* __restrict__ Wc,
    float* __restrict__ molOut)
{
  int atom = blockIdx.x * 256 + threadIdx.x;
  int lane = threadIdx.x & 63;
  float sum = 0.f;
  #pragma unroll
  for (int p = 0; p < 8; p++) sum += pacc[(size_t)p * NA + atom];
  float val = sum * (1.f / 128.f) + Wc[numbers[atom]];
  int mol = batch[atom];
  int m0 = __shfl(mol, 0, 64);
  int m63 = __shfl(mol, 63, 64);
  if (m0 == m63){
    #pragma unroll
    for (int m = 32; m; m >>= 1) val += __shfl_xor(val, m, 64);
    if (lane == 0) atomic_add_f(&molOut[mol], val);
  } else {
    atomic_add_f(&molOut[mol], val);
  }
}

extern "C" void kernel_launch(void* const* d_in, const int* in_sizes, int n_in,
                              void* d_out, int out_size, void* d_ws, size_t ws_size,
                              hipStream_t stream)
{
  const float* pos     = (const float*)d_in[0];
  const float* cells   = (const float*)d_in[1];
  const int*   numbers = (const int*)d_in[2];
  const int*   ei      = (const int*)d_in[3];
  const float* eoff    = (const float*)d_in[4];
  const int*   batch   = (const int*)d_in[5];
  const float* U       = (const float*)d_in[6];
  const float* gamma   = (const float*)d_in[7];
  const float* beta    = (const float*)d_in[8];
  const float* W1      = (const float*)d_in[9];
  const float* W2      = (const float*)d_in[10];
  const float* W3      = (const float*)d_in[11];
  const float* Wc      = (const float*)d_in[12];
  float* out = (float*)d_out;

  char* ws = (char*)d_ws;
  size_t off = 0;
  auto alloc = [&](size_t bytes) -> void* {
    void* p = ws + off;
    off += (bytes + 255) & ~(size_t)255;
    return p;
  };
  unsigned short* ps   = (unsigned short*)alloc((size_t)NA * FR * 2);      // 88 MB
  unsigned short* pbuf = (unsigned short*)alloc((size_t)2 * NA * 512 * 2); // 32 MB
  float* stats         = (float*)alloc((size_t)NA * 2 * 4);
  unsigned short* Wg1  = (unsigned short*)alloc((size_t)4 * 512 * FR * 2); // 11 MB
  float* gW            = (float*)alloc(4 * 512 * 4);
  float* bW            = (float*)alloc(4 * 512 * 4);
  unsigned short* W2t  = (unsigned short*)alloc((size_t)4 * 512 * 512 * 2);
  float* W3s           = (float*)alloc(4 * 512 * 4);
  unsigned short* h1   = (unsigned short*)alloc((size_t)NA * 512 * 2);
  float* pacc          = (float*)alloc((size_t)8 * NA * 4);
  int* list            = (int*)alloc(NA * 4);
  int* perm            = (int*)alloc((size_t)NE * 4);
  int* startsK         = (int*)alloc((65536 + 1) * 4);
  int* cnt64k          = (int*)alloc(65536 * 4);
  int* cursor64k       = (int*)alloc(65536 * 4);
  int* bsum            = (int*)alloc(256 * 4);
  int* boff            = (int*)alloc(256 * 4);
  int* bhist           = (int*)alloc(64 * 4 * 4);
  int* boffs           = (int*)alloc(64 * 4 * 4);
  int* ints            = (int*)alloc(64);
  int* cnt = ints; int* offs = ints + 8;

  hipMemsetAsync(cnt64k, 0, 65536 * 4, stream);
  hipMemsetAsync(gW, 0, 4 * 512 * 4, stream);
  hipMemsetAsync(bW, 0, 4 * 512 * 4, stream);
  hipMemsetAsync(out, 0, (size_t)out_size * 4, stream);

  // edge counting sort by (recv, sender-species)
  k_hist<<<NE / 256, 256, 0, stream>>>(ei, numbers, cnt64k);
  k_scanA<<<256, 256, 0, stream>>>(cnt64k, bsum);
  k_scanB<<<1, 256, 0, stream>>>(bsum, boff, startsK);
  k_scanC<<<256, 256, 0, stream>>>(cnt64k, boff, startsK, cursor64k);
  k_sortperm<<<NE / 256, 256, 0, stream>>>(ei, numbers, cursor64k, perm);

  // atom species grouping: contention-free stable counting sort
  k_acount<<<NA / 256, 256, 0, stream>>>(numbers, bhist);
  k_aoffs<<<1, 64, 0, stream>>>(bhist, boffs, ints);
  k_aplace<<<NA / 256, 256, 0, stream>>>(numbers, boffs, list);

  // fused edge-accumulate + U-mix + 4x4-tiled folded ps + LN stats
  k_atom<<<NA, 384, 0, stream>>>(pos, cells, ei, eoff, batch, startsK, perm, U, ps, stats);

  // weight prep (folded, block layout, K = 2688)
  k_wg1<<<dim3(8, 42, 4), 256, 0, stream>>>(W1, U, gamma, beta, Wg1, gW, bW);
  k_w2t<<<dim3(8, 8, 4), 256, 0, stream>>>(W2, U, W2t);
  k_w3<<<8, 256, 0, stream>>>(W3, U, W3s);

  // GEMM1 split-K=2 (K=2688), then LN+silu epilogue
  k_gemm<0, 2><<<1088, 256, 0, stream>>>(ps, FR, FR, Wg1, list, offs, cnt,
                                         pbuf, nullptr, nullptr);
  k_epi<<<NA / 4, 256, 0, stream>>>(pbuf, stats, gW, bW, numbers, h1);

  // GEMM2 with fused silu + W3 dot -> per-atom partials (atomic-free)
  k_gemm<2, 1><<<544, 256, 0, stream>>>(h1, 512, 512, W2t, list, offs, cnt,
                                        nullptr, W3s, pacc);
  k_final2<<<NA / 256, 256, 0, stream>>>(pacc, numbers, batch, Wc, out);
}

// Round 14
// 326.125 us; speedup vs baseline: 1.1115x; 1.0162x over previous
//
#include <hip/hip_runtime.h>

#define NA   16384
#define NE   524288
#define NM   256
#define FF   4800
#define FR   2688   // folded K: 55 pair-blocks * 48 + 48 pad ; f' = b*48 + l*16 + qi*4 + pi
#define HH   512
#define NMX  10
#define NSPH 9

typedef __bf16 bf16x8 __attribute__((ext_vector_type(8)));
typedef float  f32x4  __attribute__((ext_vector_type(4)));
typedef unsigned short u16x8 __attribute__((ext_vector_type(8)));

__device__ inline unsigned short f2bf(float x){
  unsigned int u = __builtin_bit_cast(unsigned int, x);
  u += 0x7fffu + ((u >> 16) & 1u);
  return (unsigned short)(u >> 16);
}
__device__ inline float bf2f(unsigned short h){
  unsigned int u = ((unsigned int)h) << 16;
  return __builtin_bit_cast(float, u);
}
__device__ inline void atomic_add_f(float* p, float v){
  __hip_atomic_fetch_add(p, v, __ATOMIC_RELAXED, __HIP_MEMORY_SCOPE_AGENT);
}
__device__ inline void gload16(const void* g, void* l){
  __builtin_amdgcn_global_load_lds(
      (const __attribute__((address_space(1))) unsigned int*)g,
      (__attribute__((address_space(3))) unsigned int*)l, 16, 0, 0);
}
__device__ inline float silu(float x){ return x / (1.f + __expf(-x)); }

// decode pair-block b (0..54) -> (qb, pb), qb <= pb < 10
__device__ inline void decode_blk(int b, int& qb, int& pb){
  int q = 0, rem = b;
  while (rem >= 10 - q){ rem -= 10 - q; q++; }
  qb = q; pb = q + rem;
}

// compute one 4x4 pair block for one l (CNT components), static indexing only
template<int CNT>
__device__ inline void ps_block(const float* __restrict__ cl, int qb, int pb, int off,
                                float nrm, bool diag, unsigned short* ob,
                                float& s1, float& s2){
  float cq[4][CNT], cp[4][CNT];
  #pragma unroll
  for (int i = 0; i < 4; i++)
    #pragma unroll
    for (int k = 0; k < CNT; k++){
      cq[i][k] = cl[(qb*4 + i)*9 + off + k];
      cp[i][k] = cl[(pb*4 + i)*9 + off + k];
    }
  #pragma unroll
  for (int qi = 0; qi < 4; qi++)
    #pragma unroll
    for (int pi = 0; pi < 4; pi++){
      float v = 0.f;
      #pragma unroll
      for (int k = 0; k < CNT; k++) v += cq[qi][k] * cp[pi][k];
      v *= nrm;
      float wgt = diag ? ((qi < pi) ? 2.f : ((qi == pi) ? 1.f : 0.f)) : 2.f;
      if (diag && qi > pi) v = 0.f;
      ob[qi*4 + pi] = f2bf(v);
      s1 += wgt * v;
      s2 += wgt * v * v;
    }
}

__device__ inline int block_scan_excl(int v, int tid, int* lds){
  int lane = tid & 63, w = tid >> 6;
  int x = v;
  #pragma unroll
  for (int d = 1; d < 64; d <<= 1){
    int y = __shfl_up(x, d, 64);
    if (lane >= d) x += y;
  }
  if (lane == 63) lds[w] = x;
  __syncthreads();
  int wsum = 0;
  for (int i = 0; i < w; i++) wsum += lds[i];
  return wsum + x - v;
}

// ---------------- edge counting sort by key = recv*4 + species(sender) ----------------
__global__ __launch_bounds__(256) void k_hist(const int* __restrict__ ei,
                                              const int* __restrict__ numbers,
                                              int* __restrict__ cnt64k){
  int e = blockIdx.x * 256 + threadIdx.x;
  if (e < NE){
    int key = ei[NE + e] * 4 + numbers[ei[e]];
    atomicAdd(&cnt64k[key], 1);
  }
}

__global__ __launch_bounds__(256) void k_scanA(const int* __restrict__ cnt64k,
                                               int* __restrict__ bsum){
  __shared__ int lds[4];
  int tid = threadIdx.x;
  int v = cnt64k[blockIdx.x * 256 + tid];
  int lane = tid & 63;
  #pragma unroll
  for (int m = 32; m; m >>= 1) v += __shfl_xor(v, m, 64);
  if (lane == 0) lds[tid >> 6] = v;
  __syncthreads();
  if (tid == 0) bsum[blockIdx.x] = lds[0] + lds[1] + lds[2] + lds[3];
}

__global__ __launch_bounds__(256) void k_scanB(const int* __restrict__ bsum,
                                               int* __restrict__ boff, int* __restrict__ starts){
  __shared__ int lds[4];
  int tid = threadIdx.x;
  int v = bsum[tid];
  int e = block_scan_excl(v, tid, lds);
  boff[tid] = e;
  if (tid == 0) starts[65536] = NE;
}

__global__ __launch_bounds__(256) void k_scanC(const int* __restrict__ cnt64k,
                                               const int* __restrict__ boff,
                                               int* __restrict__ starts, int* __restrict__ cursor){
  __shared__ int lds[4];
  int tid = threadIdx.x;
  int bin = blockIdx.x * 256 + tid;
  int v = cnt64k[bin];
  int e = block_scan_excl(v, tid, lds) + boff[blockIdx.x];
  starts[bin] = e;
  cursor[bin] = e;
}

__global__ __launch_bounds__(256) void k_sortperm(const int* __restrict__ ei,
                                                  const int* __restrict__ numbers,
                                                  int* __restrict__ cursor, int* __restrict__ perm){
  int e = blockIdx.x * 256 + threadIdx.x;
  if (e < NE){
    int key = ei[NE + e] * 4 + numbers[ei[e]];
    int p = atomicAdd(&cursor[key], 1);
    perm[p] = e;
  }
}

// ---------------- species grouping of atoms (contention-free counting sort) -----------
__global__ __launch_bounds__(256) void k_acount(const int* __restrict__ numbers,
                                                int* __restrict__ bhist){
  __shared__ int h[4];
  int tid = threadIdx.x;
  if (tid < 4) h[tid] = 0;
  __syncthreads();
  atomicAdd(&h[numbers[blockIdx.x * 256 + tid]], 1);
  __syncthreads();
  if (tid < 4) bhist[blockIdx.x * 4 + tid] = h[tid];
}

__global__ void k_aoffs(const int* __restrict__ bhist, int* __restrict__ boffs,
                        int* __restrict__ ints){
  if (threadIdx.x == 0){
    int* cnt = ints; int* offs = ints + 8;
    int tot[4] = {0,0,0,0};
    for (int b = 0; b < 64; b++)
      for (int s = 0; s < 4; s++) tot[s] += bhist[b*4 + s];
    int o = 0;
    for (int s = 0; s < 4; s++){ cnt[s] = tot[s]; offs[s] = o; o += tot[s]; }
    offs[4] = o;
    int run[4];
    for (int s = 0; s < 4; s++) run[s] = offs[s];
    for (int b = 0; b < 64; b++)
      for (int s = 0; s < 4; s++){ boffs[b*4 + s] = run[s]; run[s] += bhist[b*4 + s]; }
  }
}

__global__ __launch_bounds__(256) void k_aplace(const int* __restrict__ numbers,
                                                const int* __restrict__ boffs,
                                                int* __restrict__ list){
  __shared__ int ws[4][4];
  int tid = threadIdx.x, w = tid >> 6, lane = tid & 63;
  int i = blockIdx.x * 256 + tid;
  int sp = numbers[i];
  int rank = 0;
  #pragma unroll
  for (int s = 0; s < 4; s++){
    unsigned long long m = __ballot(sp == s);
    if (s == sp) rank = __popcll(m & (((unsigned long long)1 << lane) - 1));
    if (lane == 0) ws[w][s] = __popcll(m);
  }
  __syncthreads();
  int pre = 0;
  for (int w2 = 0; w2 < w; w2++) pre += ws[w2][sp];
  list[boffs[blockIdx.x * 4 + sp] + pre + rank] = i;
}

// ---------------- fused per-atom: edge accum -> U-mix -> 4x4-tiled folded ps + stats --
__global__ __launch_bounds__(384) void k_atom(
    const float* __restrict__ pos, const float* __restrict__ cells,
    const int* __restrict__ ei, const float* __restrict__ eoff,
    const int* __restrict__ batch, const int* __restrict__ startsK,
    const int* __restrict__ perm, const float* __restrict__ U,
    unsigned short* __restrict__ ps, float* __restrict__ stats)
{
  __shared__ float Rl[64][NMX];
  __shared__ float Yl[64][NSPH];
  __shared__ float csr[360];
  __shared__ float cl[360];
  __shared__ float red[16];
  __shared__ float ul[16];
  int atom = blockIdx.x;
  int tid = threadIdx.x;
  if (tid < 16) ul[tid] = U[tid];
  int e0 = startsK[atom * 4], e1 = startsK[atom * 4 + 4];
  float px = pos[atom*3+0], py = pos[atom*3+1], pz = pos[atom*3+2];
  int sp = tid / 90, n = (tid % 90) / 9, k = tid % 9;
  int aS = 0, aE = 0;
  if (tid < 360){ aS = startsK[atom * 4 + sp]; aE = startsK[atom * 4 + sp + 1]; }
  float acc = 0.f;
  for (int base = e0; base < e1; base += 64){
    int nch = min(64, e1 - base);
    if (tid < nch){
      int e = perm[base + tid];
      int snd = ei[e];
      const float* C = cells + (size_t)batch[snd] * 9;
      float o0 = eoff[e*3+0], o1 = eoff[e*3+1], o2 = eoff[e*3+2];
      float rx = px - pos[snd*3+0] + o0*C[0] + o1*C[3] + o2*C[6];
      float ry = py - pos[snd*3+1] + o0*C[1] + o1*C[4] + o2*C[7];
      float rz = pz - pos[snd*3+2] + o0*C[2] + o1*C[5] + o2*C[8];
      float r = sqrtf(rx*rx + ry*ry + rz*rz + 1e-12f);
      float inv = 1.f / r;
      float hx = rx*inv, hy = ry*inv, hz = rz*inv;
      float fc = (r < 5.f) ? (0.5f * (__cosf(r * 0.6283185307179586f) + 1.f)) : 0.f;
      #pragma unroll
      for (int nn = 0; nn < NMX; nn++){
        float d = r - (5.f/9.f) * (float)nn;
        Rl[tid][nn] = __expf(-2.f * d * d) * fc;
      }
      Yl[tid][0] = 0.28209479177387814f;
      Yl[tid][1] = 0.4886025119029199f * hy;
      Yl[tid][2] = 0.4886025119029199f * hz;
      Yl[tid][3] = 0.4886025119029199f * hx;
      Yl[tid][4] = 1.0925484305920792f * hx * hy;
      Yl[tid][5] = 1.0925484305920792f * hy * hz;
      Yl[tid][6] = 0.31539156525252005f * (3.f * hz * hz - 1.f);
      Yl[tid][7] = 1.0925484305920792f * hx * hz;
      Yl[tid][8] = 0.5462742152960396f * (hx * hx - hy * hy);
    }
    __syncthreads();
    if (tid < 360){
      int lo2 = max(aS, base), hi2 = min(aE, base + nch);
      for (int e = lo2; e < hi2; e++){
        int j = e - base;
        acc += Rl[j][n] * Yl[j][k];
      }
    }
    __syncthreads();
  }
  if (tid < 360) csr[tid] = acc;
  __syncthreads();
  if (tid < 360){
    int a = tid / 90, nk = tid % 90;
    cl[tid] = ul[a*4+0]*csr[nk] + ul[a*4+1]*csr[90+nk]
            + ul[a*4+2]*csr[180+nk] + ul[a*4+3]*csr[270+nk];
  }
  __syncthreads();
  float s1 = 0.f, s2 = 0.f;
  // ps: waves 0..2 handle l = wave; lane b < 55 does pair-block b (4x4 pairs, 16 outs)
  int l = tid >> 6, b = tid & 63;
  if (l < 3 && b < 55){
    int qb, pb;
    decode_blk(b, qb, pb);
    bool diag = (qb == pb);
    unsigned short ob[16];
    if (l == 0)      ps_block<1>(cl, qb, pb, 0, 1.f, diag, ob, s1, s2);
    else if (l == 1) ps_block<3>(cl, qb, pb, 1, 0.5773502691896258f, diag, ob, s1, s2);
    else             ps_block<5>(cl, qb, pb, 4, 0.4472135954999579f, diag, ob, s1, s2);
    unsigned short* dst = ps + (size_t)atom * FR + b * 48 + l * 16;
    *reinterpret_cast<u16x8*>(dst)     = *(const u16x8*)&ob[0];
    *reinterpret_cast<u16x8*>(dst + 8) = *(const u16x8*)&ob[8];
  } else if (tid >= 192 && tid < 198){
    unsigned short zb[8] = {0,0,0,0,0,0,0,0};
    *reinterpret_cast<u16x8*>(ps + (size_t)atom * FR + 2640 + (tid - 192) * 8) = *(const u16x8*)zb;
  }
  #pragma unroll
  for (int m = 32; m; m >>= 1){ s1 += __shfl_xor(s1, m, 64); s2 += __shfl_xor(s2, m, 64); }
  int w = tid >> 6, lane = tid & 63;
  if (lane == 0){ red[w] = s1; red[8 + w] = s2; }
  __syncthreads();
  if (tid == 0){
    float t1 = 0.f, t2 = 0.f;
    for (int i = 0; i < 6; i++){ t1 += red[i]; t2 += red[8 + i]; }
    float mean = t1 * (1.f / FF);
    float var = t2 * (1.f / FF) - mean * mean;
    var = fmaxf(var, 0.f);
    stats[2*atom]   = mean;
    stats[2*atom+1] = rsqrtf(var + 1e-5f);
  }
}

// ---------------- weight prep v3: SINGLE pass over W1, all 4 species at once ----------
// Wg[s][n][f'], f' = b*48 + l*16 + qi*4 + pi. Each W1 element read exactly once.
__global__ __launch_bounds__(256) void k_wg3(
    const float* __restrict__ W1, const float* __restrict__ U,
    const float* __restrict__ gamma, const float* __restrict__ beta,
    unsigned short* __restrict__ Wg, float* __restrict__ gW, float* __restrict__ bW)
{
  __shared__ unsigned short og[4][64][64]; // [s][fi][ni], 32 KB
  int n0 = blockIdx.x * 64, f0 = blockIdx.y * 64;
  int tid = threadIdx.x, ni = tid & 63;
  float u[4][4];
  #pragma unroll
  for (int a = 0; a < 4; a++)
    #pragma unroll
    for (int s = 0; s < 4; s++) u[a][s] = U[a*4 + s];
  float gs[4] = {0,0,0,0}, bs[4] = {0,0,0,0};
  for (int rep = 0; rep < 16; rep++){
    int fi = rep * 4 + (tid >> 6);
    int fp = f0 + fi;
    int b = fp / 48, r = fp % 48;
    int l = r >> 4, qi = (r >> 2) & 3, pi = r & 3;
    float tg[4] = {0,0,0,0}, tb[4] = {0,0,0,0};
    if (b < 55){
      int qb, pb;
      decode_blk(b, qb, pb);
      bool zero = (qb == pb) && (qi > pi);
      if (!zero){
        int q = qb*4 + qi, p = pb*4 + pi;
        int fa = (q * 40 + p) * 3 + l;
        float ga = gamma[fa], ba = beta[fa];
        float wm[4] = {0,0,0,0};
        #pragma unroll
        for (int a = 0; a < 4; a++){
          float wa = W1[(size_t)a * FF * 512 + (size_t)fa * 512 + n0 + ni];
          #pragma unroll
          for (int s = 0; s < 4; s++) wm[s] += u[a][s] * wa;
        }
        #pragma unroll
        for (int s = 0; s < 4; s++){ tg[s] = ga * wm[s]; tb[s] = ba * wm[s]; }
        if (p != q){
          int fb = (p * 40 + q) * 3 + l;
          float gb = gamma[fb], bb = beta[fb];
          float wn[4] = {0,0,0,0};
          #pragma unroll
          for (int a = 0; a < 4; a++){
            float wb = W1[(size_t)a * FF * 512 + (size_t)fb * 512 + n0 + ni];
            #pragma unroll
            for (int s = 0; s < 4; s++) wn[s] += u[a][s] * wb;
          }
          #pragma unroll
          for (int s = 0; s < 4; s++){ tg[s] += gb * wn[s]; tb[s] += bb * wn[s]; }
        }
      }
    }
    #pragma unroll
    for (int s = 0; s < 4; s++){
      og[s][fi][ni] = f2bf(tg[s]);
      gs[s] += tg[s];
      bs[s] += tb[s];
    }
  }
  #pragma unroll
  for (int s = 0; s < 4; s++){
    atomic_add_f(&gW[s * 512 + n0 + ni], gs[s]);
    atomic_add_f(&bW[s * 512 + n0 + ni], bs[s]);
  }
  __syncthreads();
  for (int it = 0; it < 8; it++){
    int idx = it * 256 + tid;      // 2048 u16x8 chunks: [s][nn][c]
    int c = idx & 7;
    int rrow = idx >> 3;
    int s = rrow >> 6, nn = rrow & 63;
    unsigned short o[8];
    #pragma unroll
    for (int j = 0; j < 8; j++) o[j] = og[s][c*8 + j][nn];
    *reinterpret_cast<u16x8*>(&Wg[((size_t)s * 512 + n0 + nn) * FR + f0 + c * 8]) = *(const u16x8*)o;
  }
}

__global__ __launch_bounds__(256) void k_w2t(
    const float* __restrict__ W2, const float* __restrict__ U,
    unsigned short* __restrict__ W2t)
{
  __shared__ float t[64][65];
  int n0 = blockIdx.x * 64, k0 = blockIdx.y * 64, s = blockIdx.z;
  float u0 = U[s], u1 = U[4+s], u2 = U[8+s], u3 = U[12+s];
  int tid = threadIdx.x;
  #pragma unroll 4
  for (int rep = 0; rep < 16; rep++){
    int idx = rep * 256 + tid;
    int ki = idx >> 6, ni = idx & 63;
    size_t base = (size_t)(k0 + ki) * 512 + (n0 + ni);
    t[ki][ni] = u0*W2[base] + u1*W2[base + 512*512]
              + u2*W2[base + 2*512*512] + u3*W2[base + 3*512*512];
  }
  __syncthreads();
  #pragma unroll 4
  for (int rep = 0; rep < 16; rep++){
    int idx = rep * 256 + tid;
    int ni = idx >> 6, ki = idx & 63;
    W2t[((size_t)s * 512 + n0 + ni) * 512 + k0 + ki] = f2bf(t[ki][ni]);
  }
}

__global__ void k_w3(const float* __restrict__ W3, const float* __restrict__ U,
                     float* __restrict__ W3s)
{
  int idx = blockIdx.x * 256 + threadIdx.x;
  if (idx < 4 * 512){
    int s = idx >> 9, k = idx & 511;
    W3s[idx] = U[s]*W3[k] + U[4+s]*W3[512+k] + U[8+s]*W3[2*512+k] + U[12+s]*W3[3*512+k];
  }
}

// ---------------- GEMM template (128x128 tile, BK=64, bf16 MFMA) ----------------
template<int EPI, int NSPLIT>
__global__ __launch_bounds__(256) void k_gemm(
    const unsigned short* __restrict__ Ag, int lda, int K,
    const unsigned short* __restrict__ Btg,
    const int* __restrict__ list, const int* __restrict__ offs, const int* __restrict__ cnt,
    unsigned short* __restrict__ pout,
    const float* __restrict__ W3s, float* __restrict__ pacc)
{
  __shared__ alignas(16) char smem[32768];
  const int NV = 4 * NSPLIT;
  int b = blockIdx.x;
  int y = (b & 7) + 8 * (b / (8 * NV));
  int v = (b >> 3) % NV;
  int x = v & 3, kh = v >> 2;

  int s = 0, t = y;
  for (; s < 4; s++){
    int nts = (cnt[s] + 127) >> 7;
    if (t < nts) break;
    t -= nts;
  }
  if (s >= 4) return;
  int cntS = cnt[s], offS = offs[s];
  int rt = t, n0 = x * 128;
  int tid = threadIdx.x, w = tid >> 6, lane = tid & 63;
  int wr = w >> 1, wc = w & 1;

  const unsigned short* Bts = Btg + (size_t)s * 512 * K;
  const unsigned short* gA[4];
  const unsigned short* gB[4];
  char* lA[4];
  char* lB[4];
  #pragma unroll
  for (int it = 0; it < 4; it++){
    int g = it * 4 + w;
    int idx = g * 64 + lane;
    int row = idx >> 3, ch = idx & 7;
    int cg = ch ^ (row & 7);
    int gr = rt * 128 + row; gr = gr < cntS ? gr : cntS - 1;
    int atom = list[offS + gr];
    gA[it] = Ag + (size_t)atom * lda + cg * 8;
    lA[it] = smem + g * 1024;
    gB[it] = Bts + (size_t)(n0 + row) * K + cg * 8;
    lB[it] = smem + 16384 + g * 1024;
  }

  int hi = lane >> 4, lo = lane & 15;
  f32x4 acc[4][4];
  #pragma unroll
  for (int mi = 0; mi < 4; mi++)
    #pragma unroll
    for (int ni = 0; ni < 4; ni++)
      #pragma unroll
      for (int r = 0; r < 4; r++) acc[mi][ni][r] = 0.f;

  int abase[4], a7[4], bbase[4], b7[4];
  #pragma unroll
  for (int mi = 0; mi < 4; mi++){ int row = wr*64 + mi*16 + lo; abase[mi] = row*128; a7[mi] = row & 7; }
  #pragma unroll
  for (int ni = 0; ni < 4; ni++){ int row = wc*64 + ni*16 + lo; bbase[ni] = 16384 + row*128; b7[ni] = row & 7; }

  int nk = K / 64;
  int k0 = ((nk * kh) / NSPLIT) * 64;
  int k1 = ((nk * (kh + 1)) / NSPLIT) * 64;

  for (int kt = k0; kt < k1; kt += 64){
    #pragma unroll
    for (int it = 0; it < 4; it++) gload16(gA[it] + kt, lA[it]);
    #pragma unroll
    for (int it = 0; it < 4; it++) gload16(gB[it] + kt, lB[it]);
    __syncthreads();
    #pragma unroll
    for (int kk = 0; kk < 2; kk++){
      bf16x8 af[4], bfr[4];
      #pragma unroll
      for (int mi = 0; mi < 4; mi++)
        af[mi] = *(const bf16x8*)(smem + abase[mi] + (((kk*4 + hi) ^ a7[mi]) << 4));
      #pragma unroll
      for (int ni = 0; ni < 4; ni++)
        bfr[ni] = *(const bf16x8*)(smem + bbase[ni] + (((kk*4 + hi) ^ b7[ni]) << 4));
      #pragma unroll
      for (int mi = 0; mi < 4; mi++)
        #pragma unroll
        for (int ni = 0; ni < 4; ni++)
          acc[mi][ni] = __builtin_amdgcn_mfma_f32_16x16x32_bf16(af[mi], bfr[ni], acc[mi][ni], 0, 0, 0);
    }
    __syncthreads();
  }

  int gn[4];
  #pragma unroll
  for (int ni = 0; ni < 4; ni++) gn[ni] = n0 + wc*64 + ni*16 + lo;

  if (EPI == 0){
    #pragma unroll
    for (int mi = 0; mi < 4; mi++){
      #pragma unroll
      for (int j = 0; j < 4; j++){
        int gr = rt*128 + wr*64 + mi*16 + hi*4 + j;
        if (gr < cntS){
          int atom = list[offS + gr];
          #pragma unroll
          for (int ni = 0; ni < 4; ni++)
            pout[((size_t)kh * NA + atom) * 512 + gn[ni]] = f2bf(acc[mi][ni][j]);
        }
      }
    }
  } else {
    float w3v[4];
    #pragma unroll
    for (int ni = 0; ni < 4; ni++) w3v[ni] = W3s[s * 512 + gn[ni]];
    float* pslot = pacc + (size_t)(x * 2 + wc) * NA;
    #pragma unroll
    for (int mi = 0; mi < 4; mi++){
      #pragma unroll
      for (int j = 0; j < 4; j++){
        int gr = rt*128 + wr*64 + mi*16 + hi*4 + j;
        if (gr < cntS){
          int atom = list[offS + gr];
          float pdot = 0.f;
          #pragma unroll
          for (int ni = 0; ni < 4; ni++)
            pdot += silu(acc[mi][ni][j]) * w3v[ni];
          pdot += __shfl_xor(pdot, 1, 16);
          pdot += __shfl_xor(pdot, 2, 16);
          pdot += __shfl_xor(pdot, 4, 16);
          pdot += __shfl_xor(pdot, 8, 16);
          if (lo == 0) pslot[atom] = pdot;
        }
      }
    }
  }
}

// ---------------- epilogue: combine 4 split-K partials + LN-affine + silu -> h1 -------
__global__ __launch_bounds__(256) void k_epi(
    const unsigned short* __restrict__ pbuf, const float* __restrict__ stats,
    const float* __restrict__ gW, const float* __restrict__ bW,
    const int* __restrict__ numbers, unsigned short* __restrict__ h1)
{
  int w = threadIdx.x >> 6, lane = threadIdx.x & 63;
  int atom = blockIdx.x * 4 + w;
  int s = numbers[atom];
  float mean = stats[2*atom], rstd = stats[2*atom+1];
  int c0 = lane * 8;
  u16x8 a0 = *reinterpret_cast<const u16x8*>(pbuf + (size_t)atom * 512 + c0);
  u16x8 a1 = *reinterpret_cast<const u16x8*>(pbuf + (size_t)(NA + atom) * 512 + c0);
  u16x8 a2 = *reinterpret_cast<const u16x8*>(pbuf + (size_t)(2*NA + atom) * 512 + c0);
  u16x8 a3 = *reinterpret_cast<const u16x8*>(pbuf + (size_t)(3*NA + atom) * 512 + c0);
  unsigned short o[8];
  #pragma unroll
  for (int j = 0; j < 8; j++){
    int c = c0 + j;
    float acc = (bf2f(a0[j]) + bf2f(a1[j])) + (bf2f(a2[j]) + bf2f(a3[j]));
    float vv = rstd * acc + bW[s*512 + c] - mean * rstd * gW[s*512 + c];
    o[j] = f2bf(silu(vv));
  }
  *reinterpret_cast<u16x8*>(h1 + (size_t)atom * 512 + c0) = *(const u16x8*)o;
}

// ---------------- final: sum 8 pacc partials/atom, wave-uniform molecule atomic -------
__global__ __launch_bounds__(256) void k_final2(
    const float* __restrict__ pacc, const int* __restrict__ numbers,
    const int* __restrict__ batch, const float* __restrict__ Wc,
    float* __restrict__ molOut)
{
  int atom = blockIdx.x * 256 + threadIdx.x;
  int lane = threadIdx.x & 63;
  float sum = 0.f;
  #pragma unroll
  for (int p = 0; p < 8; p++) sum += pacc[(size_t)p * NA + atom];
  float val = sum * (1.f / 128.f) + Wc[numbers[atom]];
  int mol = batch[atom];
  int m0 = __shfl(mol, 0, 64);
  int m63 = __shfl(mol, 63, 64);
  if (m0 == m63){
    #pragma unroll
    for (int m = 32; m; m >>= 1) val += __shfl_xor(val, m, 64);
    if (lane == 0) atomic_add_f(&molOut[mol], val);
  } else {
    atomic_add_f(&molOut[mol], val);
  }
}

extern "C" void kernel_launch(void* const* d_in, const int* in_sizes, int n_in,
                              void* d_out, int out_size, void* d_ws, size_t ws_size,
                              hipStream_t stream)
{
  const float* pos     = (const float*)d_in[0];
  const float* cells   = (const float*)d_in[1];
  const int*   numbers = (const int*)d_in[2];
  const int*   ei      = (const int*)d_in[3];
  const float* eoff    = (const float*)d_in[4];
  const int*   batch   = (const int*)d_in[5];
  const float* U       = (const float*)d_in[6];
  const float* gamma   = (const float*)d_in[7];
  const float* beta    = (const float*)d_in[8];
  const float* W1      = (const float*)d_in[9];
  const float* W2      = (const float*)d_in[10];
  const float* W3      = (const float*)d_in[11];
  const float* Wc      = (const float*)d_in[12];
  float* out = (float*)d_out;

  char* ws = (char*)d_ws;
  size_t off = 0;
  auto alloc = [&](size_t bytes) -> void* {
    void* p = ws + off;
    off += (bytes + 255) & ~(size_t)255;
    return p;
  };
  unsigned short* ps   = (unsigned short*)alloc((size_t)NA * FR * 2);      // 88 MB
  unsigned short* pbuf = (unsigned short*)alloc((size_t)4 * NA * 512 * 2); // 64 MB
  float* stats         = (float*)alloc((size_t)NA * 2 * 4);
  unsigned short* Wg1  = (unsigned short*)alloc((size_t)4 * 512 * FR * 2); // 11 MB
  unsigned short* W2t  = (unsigned short*)alloc((size_t)4 * 512 * 512 * 2);
  float* W3s           = (float*)alloc(4 * 512 * 4);
  unsigned short* h1   = (unsigned short*)alloc((size_t)NA * 512 * 2);
  float* pacc          = (float*)alloc((size_t)8 * NA * 4);
  int* list            = (int*)alloc(NA * 4);
  int* perm            = (int*)alloc((size_t)NE * 4);
  int* startsK         = (int*)alloc((65536 + 1) * 4);
  // contiguous zero-init region: cnt64k + gW + bW (one memset)
  int* cnt64k          = (int*)alloc(65536 * 4);
  float* gW            = (float*)alloc(4 * 512 * 4);
  float* bW            = (float*)alloc(4 * 512 * 4);
  int* cursor64k       = (int*)alloc(65536 * 4);
  int* bsum            = (int*)alloc(256 * 4);
  int* boff            = (int*)alloc(256 * 4);
  int* bhist           = (int*)alloc(64 * 4 * 4);
  int* boffs           = (int*)alloc(64 * 4 * 4);
  int* ints            = (int*)alloc(64);
  int* cnt = ints; int* offs = ints + 8;

  hipMemsetAsync(cnt64k, 0, 65536 * 4 + 2 * 4 * 512 * 4, stream);
  hipMemsetAsync(out, 0, (size_t)out_size * 4, stream);

  // edge counting sort by (recv, sender-species)
  k_hist<<<NE / 256, 256, 0, stream>>>(ei, numbers, cnt64k);
  k_scanA<<<256, 256, 0, stream>>>(cnt64k, bsum);
  k_scanB<<<1, 256, 0, stream>>>(bsum, boff, startsK);
  k_scanC<<<256, 256, 0, stream>>>(cnt64k, boff, startsK, cursor64k);
  k_sortperm<<<NE / 256, 256, 0, stream>>>(ei, numbers, cursor64k, perm);

  // atom species grouping: contention-free stable counting sort
  k_acount<<<NA / 256, 256, 0, stream>>>(numbers, bhist);
  k_aoffs<<<1, 64, 0, stream>>>(bhist, boffs, ints);
  k_aplace<<<NA / 256, 256, 0, stream>>>(numbers, boffs, list);

  // fused edge-accumulate + U-mix + 4x4-tiled folded ps + LN stats
  k_atom<<<NA, 384, 0, stream>>>(pos, cells, ei, eoff, batch, startsK, perm, U, ps, stats);

  // weight prep (single pass over W1; W2 mix; W3 mix)
  k_wg3<<<dim3(8, 42), 256, 0, stream>>>(W1, U, gamma, beta, Wg1, gW, bW);
  k_w2t<<<dim3(8, 8, 4), 256, 0, stream>>>(W2, U, W2t);
  k_w3<<<8, 256, 0, stream>>>(W3, U, W3s);

  // GEMM1 split-K=4 (K=2688, 2176 blocks), then LN+silu epilogue
  k_gemm<0, 4><<<2176, 256, 0, stream>>>(ps, FR, FR, Wg1, list, offs, cnt,
                                         pbuf, nullptr, nullptr);
  k_epi<<<NA / 4, 256, 0, stream>>>(pbuf, stats, gW, bW, numbers, h1);

  // GEMM2 with fused silu + W3 dot -> per-atom partials (atomic-free)
  k_gemm<2, 1><<<544, 256, 0, stream>>>(h1, 512, 512, W2t, list, offs, cnt,
                                        nullptr, W3s, pacc);
  k_final2<<<NA / 256, 256, 0, stream>>>(pacc, numbers, batch, Wc, out);
}

// Round 15
// 318.999 us; speedup vs baseline: 1.1363x; 1.0223x over previous
//
#include <hip/hip_runtime.h>

#define NA   16384
#define NE   524288
#define NM   256
#define FF   4800
#define FR   2688   // folded K: 55 pair-blocks * 48 + 48 pad ; f' = b*48 + l*16 + qi*4 + pi
#define HH   512
#define NMX  10
#define NSPH 9

typedef __bf16 bf16x8 __attribute__((ext_vector_type(8)));
typedef float  f32x4  __attribute__((ext_vector_type(4)));
typedef unsigned short u16x8 __attribute__((ext_vector_type(8)));

__device__ inline unsigned short f2bf(float x){
  unsigned int u = __builtin_bit_cast(unsigned int, x);
  u += 0x7fffu + ((u >> 16) & 1u);
  return (unsigned short)(u >> 16);
}
__device__ inline float bf2f(unsigned short h){
  unsigned int u = ((unsigned int)h) << 16;
  return __builtin_bit_cast(float, u);
}
__device__ inline void atomic_add_f(float* p, float v){
  __hip_atomic_fetch_add(p, v, __ATOMIC_RELAXED, __HIP_MEMORY_SCOPE_AGENT);
}
__device__ inline void gload16(const void* g, void* l){
  __builtin_amdgcn_global_load_lds(
      (const __attribute__((address_space(1))) unsigned int*)g,
      (__attribute__((address_space(3))) unsigned int*)l, 16, 0, 0);
}
__device__ inline float silu(float x){ return x / (1.f + __expf(-x)); }

// decode pair-block b (0..54) -> (qb, pb), qb <= pb < 10
__device__ inline void decode_blk(int b, int& qb, int& pb){
  int q = 0, rem = b;
  while (rem >= 10 - q){ rem -= 10 - q; q++; }
  qb = q; pb = q + rem;
}

// full 4x4 pair block for one l (CNT components)
template<int CNT>
__device__ inline void ps_block(const float* __restrict__ cl, int qb, int pb, int off,
                                float nrm, bool diag, unsigned short* ob,
                                float& s1, float& s2){
  float cq[4][CNT], cp[4][CNT];
  #pragma unroll
  for (int i = 0; i < 4; i++)
    #pragma unroll
    for (int k = 0; k < CNT; k++){
      cq[i][k] = cl[(qb*4 + i)*9 + off + k];
      cp[i][k] = cl[(pb*4 + i)*9 + off + k];
    }
  #pragma unroll
  for (int qi = 0; qi < 4; qi++)
    #pragma unroll
    for (int pi = 0; pi < 4; pi++){
      float v = 0.f;
      #pragma unroll
      for (int k = 0; k < CNT; k++) v += cq[qi][k] * cp[pi][k];
      v *= nrm;
      float wgt = diag ? ((qi < pi) ? 2.f : ((qi == pi) ? 1.f : 0.f)) : 2.f;
      if (diag && qi > pi) v = 0.f;
      ob[qi*4 + pi] = f2bf(v);
      s1 += wgt * v;
      s2 += wgt * v * v;
    }
}

// half (2 qi rows x 4 pi) of a 4x4 pair block: 8 outputs
template<int CNT>
__device__ inline void ps_block_half(const float* __restrict__ cl, int qb, int pb, int off,
                                     float nrm, bool diag, int qh, unsigned short* ob,
                                     float& s1, float& s2){
  float cq[2][CNT], cp[4][CNT];
  #pragma unroll
  for (int i = 0; i < 2; i++)
    #pragma unroll
    for (int k = 0; k < CNT; k++)
      cq[i][k] = cl[(qb*4 + qh*2 + i)*9 + off + k];
  #pragma unroll
  for (int i = 0; i < 4; i++)
    #pragma unroll
    for (int k = 0; k < CNT; k++)
      cp[i][k] = cl[(pb*4 + i)*9 + off + k];
  #pragma unroll
  for (int qi = 0; qi < 2; qi++)
    #pragma unroll
    for (int pi = 0; pi < 4; pi++){
      int qg = qh*2 + qi;
      float v = 0.f;
      #pragma unroll
      for (int k = 0; k < CNT; k++) v += cq[qi][k] * cp[pi][k];
      v *= nrm;
      float wgt = diag ? ((qg < pi) ? 2.f : ((qg == pi) ? 1.f : 0.f)) : 2.f;
      if (diag && qg > pi) v = 0.f;
      ob[qi*4 + pi] = f2bf(v);
      s1 += wgt * v;
      s2 += wgt * v * v;
    }
}

__device__ inline int block_scan_excl(int v, int tid, int* lds){
  int lane = tid & 63, w = tid >> 6;
  int x = v;
  #pragma unroll
  for (int d = 1; d < 64; d <<= 1){
    int y = __shfl_up(x, d, 64);
    if (lane >= d) x += y;
  }
  if (lane == 63) lds[w] = x;
  __syncthreads();
  int wsum = 0;
  for (int i = 0; i < w; i++) wsum += lds[i];
  return wsum + x - v;
}

// ---------------- edge counting sort by key = recv*4 + species(sender) ----------------
__global__ __launch_bounds__(256) void k_hist(const int* __restrict__ ei,
                                              const int* __restrict__ numbers,
                                              int* __restrict__ cnt64k){
  int e = blockIdx.x * 256 + threadIdx.x;
  if (e < NE){
    int key = ei[NE + e] * 4 + numbers[ei[e]];
    atomicAdd(&cnt64k[key], 1);
  }
}

__global__ __launch_bounds__(256) void k_scanA(const int* __restrict__ cnt64k,
                                               int* __restrict__ bsum){
  __shared__ int lds[4];
  int tid = threadIdx.x;
  int v = cnt64k[blockIdx.x * 256 + tid];
  int lane = tid & 63;
  #pragma unroll
  for (int m = 32; m; m >>= 1) v += __shfl_xor(v, m, 64);
  if (lane == 0) lds[tid >> 6] = v;
  __syncthreads();
  if (tid == 0) bsum[blockIdx.x] = lds[0] + lds[1] + lds[2] + lds[3];
}

__global__ __launch_bounds__(256) void k_scanB(const int* __restrict__ bsum,
                                               int* __restrict__ boff, int* __restrict__ starts){
  __shared__ int lds[4];
  int tid = threadIdx.x;
  int v = bsum[tid];
  int e = block_scan_excl(v, tid, lds);
  boff[tid] = e;
  if (tid == 0) starts[65536] = NE;
}

__global__ __launch_bounds__(256) void k_scanC(const int* __restrict__ cnt64k,
                                               const int* __restrict__ boff,
                                               int* __restrict__ starts, int* __restrict__ cursor){
  __shared__ int lds[4];
  int tid = threadIdx.x;
  int bin = blockIdx.x * 256 + tid;
  int v = cnt64k[bin];
  int e = block_scan_excl(v, tid, lds) + boff[blockIdx.x];
  starts[bin] = e;
  cursor[bin] = e;
}

__global__ __launch_bounds__(256) void k_sortperm(const int* __restrict__ ei,
                                                  const int* __restrict__ numbers,
                                                  int* __restrict__ cursor, int* __restrict__ perm){
  int e = blockIdx.x * 256 + threadIdx.x;
  if (e < NE){
    int key = ei[NE + e] * 4 + numbers[ei[e]];
    int p = atomicAdd(&cursor[key], 1);
    perm[p] = e;
  }
}

// ---------------- species grouping of atoms (contention-free counting sort) -----------
__global__ __launch_bounds__(256) void k_acount(const int* __restrict__ numbers,
                                                int* __restrict__ bhist){
  __shared__ int h[4];
  int tid = threadIdx.x;
  if (tid < 4) h[tid] = 0;
  __syncthreads();
  atomicAdd(&h[numbers[blockIdx.x * 256 + tid]], 1);
  __syncthreads();
  if (tid < 4) bhist[blockIdx.x * 4 + tid] = h[tid];
}

__global__ void k_aoffs(const int* __restrict__ bhist, int* __restrict__ boffs,
                        int* __restrict__ ints){
  if (threadIdx.x == 0){
    int* cnt = ints; int* offs = ints + 8;
    int tot[4] = {0,0,0,0};
    for (int b = 0; b < 64; b++)
      for (int s = 0; s < 4; s++) tot[s] += bhist[b*4 + s];
    int o = 0;
    for (int s = 0; s < 4; s++){ cnt[s] = tot[s]; offs[s] = o; o += tot[s]; }
    offs[4] = o;
    int run[4];
    for (int s = 0; s < 4; s++) run[s] = offs[s];
    for (int b = 0; b < 64; b++)
      for (int s = 0; s < 4; s++){ boffs[b*4 + s] = run[s]; run[s] += bhist[b*4 + s]; }
  }
}

__global__ __launch_bounds__(256) void k_aplace(const int* __restrict__ numbers,
                                                const int* __restrict__ boffs,
                                                int* __restrict__ list){
  __shared__ int ws[4][4];
  int tid = threadIdx.x, w = tid >> 6, lane = tid & 63;
  int i = blockIdx.x * 256 + tid;
  int sp = numbers[i];
  int rank = 0;
  #pragma unroll
  for (int s = 0; s < 4; s++){
    unsigned long long m = __ballot(sp == s);
    if (s == sp) rank = __popcll(m & (((unsigned long long)1 << lane) - 1));
    if (lane == 0) ws[w][s] = __popcll(m);
  }
  __syncthreads();
  int pre = 0;
  for (int w2 = 0; w2 < w; w2++) pre += ws[w2][sp];
  list[boffs[blockIdx.x * 4 + sp] + pre + rank] = i;
}

// ---------------- fused per-atom: edge accum -> U-mix -> 6-wave-split ps + stats ------
__global__ __launch_bounds__(384) void k_atom(
    const float* __restrict__ pos, const float* __restrict__ cells,
    const int* __restrict__ ei, const float* __restrict__ eoff,
    const int* __restrict__ batch, const int* __restrict__ startsK,
    const int* __restrict__ perm, const float* __restrict__ U,
    unsigned short* __restrict__ ps, float* __restrict__ stats)
{
  __shared__ float Rl[64][NMX];
  __shared__ float Yl[64][NSPH];
  __shared__ float csr[360];
  __shared__ float cl[360];
  __shared__ float red[16];
  __shared__ float ul[16];
  int atom = blockIdx.x;
  int tid = threadIdx.x;
  if (tid < 16) ul[tid] = U[tid];
  int e0 = startsK[atom * 4], e1 = startsK[atom * 4 + 4];
  float px = pos[atom*3+0], py = pos[atom*3+1], pz = pos[atom*3+2];
  int sp = tid / 90, n = (tid % 90) / 9, k = tid % 9;
  int aS = 0, aE = 0;
  if (tid < 360){ aS = startsK[atom * 4 + sp]; aE = startsK[atom * 4 + sp + 1]; }
  float acc = 0.f;
  for (int base = e0; base < e1; base += 64){
    int nch = min(64, e1 - base);
    if (tid < nch){
      int e = perm[base + tid];
      int snd = ei[e];
      const float* C = cells + (size_t)batch[snd] * 9;
      float o0 = eoff[e*3+0], o1 = eoff[e*3+1], o2 = eoff[e*3+2];
      float rx = px - pos[snd*3+0] + o0*C[0] + o1*C[3] + o2*C[6];
      float ry = py - pos[snd*3+1] + o0*C[1] + o1*C[4] + o2*C[7];
      float rz = pz - pos[snd*3+2] + o0*C[2] + o1*C[5] + o2*C[8];
      float r = sqrtf(rx*rx + ry*ry + rz*rz + 1e-12f);
      float inv = 1.f / r;
      float hx = rx*inv, hy = ry*inv, hz = rz*inv;
      float fc = (r < 5.f) ? (0.5f * (__cosf(r * 0.6283185307179586f) + 1.f)) : 0.f;
      #pragma unroll
      for (int nn = 0; nn < NMX; nn++){
        float d = r - (5.f/9.f) * (float)nn;
        Rl[tid][nn] = __expf(-2.f * d * d) * fc;
      }
      Yl[tid][0] = 0.28209479177387814f;
      Yl[tid][1] = 0.4886025119029199f * hy;
      Yl[tid][2] = 0.4886025119029199f * hz;
      Yl[tid][3] = 0.4886025119029199f * hx;
      Yl[tid][4] = 1.0925484305920792f * hx * hy;
      Yl[tid][5] = 1.0925484305920792f * hy * hz;
      Yl[tid][6] = 0.31539156525252005f * (3.f * hz * hz - 1.f);
      Yl[tid][7] = 1.0925484305920792f * hx * hz;
      Yl[tid][8] = 0.5462742152960396f * (hx * hx - hy * hy);
    }
    __syncthreads();
    if (tid < 360){
      int lo2 = max(aS, base), hi2 = min(aE, base + nch);
      for (int e = lo2; e < hi2; e++){
        int j = e - base;
        acc += Rl[j][n] * Yl[j][k];
      }
    }
    __syncthreads();
  }
  if (tid < 360) csr[tid] = acc;
  __syncthreads();
  if (tid < 360){
    int a = tid / 90, nk = tid % 90;
    cl[tid] = ul[a*4+0]*csr[nk] + ul[a*4+1]*csr[90+nk]
            + ul[a*4+2]*csr[180+nk] + ul[a*4+3]*csr[270+nk];
  }
  __syncthreads();
  float s1 = 0.f, s2 = 0.f;
  // ps split across all 6 waves: w0/w1 -> l=2 (qi halves), w2/w3 -> l=1, w4 -> l=0, w5 -> pad
  int w6 = tid >> 6, b = tid & 63;
  if (w6 <= 3 && b < 55){
    int l = (w6 < 2) ? 2 : 1;
    int qh = w6 & 1;
    int qb, pb;
    decode_blk(b, qb, pb);
    bool diag = (qb == pb);
    unsigned short ob[8];
    if (l == 2) ps_block_half<5>(cl, qb, pb, 4, 0.4472135954999579f, diag, qh, ob, s1, s2);
    else        ps_block_half<3>(cl, qb, pb, 1, 0.5773502691896258f, diag, qh, ob, s1, s2);
    unsigned short* dst = ps + (size_t)atom * FR + b * 48 + l * 16 + qh * 8;
    *reinterpret_cast<u16x8*>(dst) = *(const u16x8*)ob;
  } else if (w6 == 4 && b < 55){
    int qb, pb;
    decode_blk(b, qb, pb);
    bool diag = (qb == pb);
    unsigned short ob[16];
    ps_block<1>(cl, qb, pb, 0, 1.f, diag, ob, s1, s2);
    unsigned short* dst = ps + (size_t)atom * FR + b * 48;
    *reinterpret_cast<u16x8*>(dst)     = *(const u16x8*)&ob[0];
    *reinterpret_cast<u16x8*>(dst + 8) = *(const u16x8*)&ob[8];
  } else if (w6 == 5 && b < 6){
    unsigned short zb[8] = {0,0,0,0,0,0,0,0};
    *reinterpret_cast<u16x8*>(ps + (size_t)atom * FR + 2640 + b * 8) = *(const u16x8*)zb;
  }
  #pragma unroll
  for (int m = 32; m; m >>= 1){ s1 += __shfl_xor(s1, m, 64); s2 += __shfl_xor(s2, m, 64); }
  int w = tid >> 6, lane = tid & 63;
  if (lane == 0){ red[w] = s1; red[8 + w] = s2; }
  __syncthreads();
  if (tid == 0){
    float t1 = 0.f, t2 = 0.f;
    for (int i = 0; i < 6; i++){ t1 += red[i]; t2 += red[8 + i]; }
    float mean = t1 * (1.f / FF);
    float var = t2 * (1.f / FF) - mean * mean;
    var = fmaxf(var, 0.f);
    stats[2*atom]   = mean;
    stats[2*atom+1] = rsqrtf(var + 1e-5f);
  }
}

// ---------------- weight prep v3: SINGLE pass over W1, all 4 species at once ----------
__global__ __launch_bounds__(256) void k_wg3(
    const float* __restrict__ W1, const float* __restrict__ U,
    const float* __restrict__ gamma, const float* __restrict__ beta,
    unsigned short* __restrict__ Wg, float* __restrict__ gW, float* __restrict__ bW)
{
  __shared__ unsigned short og[4][64][64]; // [s][fi][ni], 32 KB
  int n0 = blockIdx.x * 64, f0 = blockIdx.y * 64;
  int tid = threadIdx.x, ni = tid & 63;
  float u[4][4];
  #pragma unroll
  for (int a = 0; a < 4; a++)
    #pragma unroll
    for (int s = 0; s < 4; s++) u[a][s] = U[a*4 + s];
  float gs[4] = {0,0,0,0}, bs[4] = {0,0,0,0};
  for (int rep = 0; rep < 16; rep++){
    int fi = rep * 4 + (tid >> 6);
    int fp = f0 + fi;
    int b = fp / 48, r = fp % 48;
    int l = r >> 4, qi = (r >> 2) & 3, pi = r & 3;
    float tg[4] = {0,0,0,0}, tb[4] = {0,0,0,0};
    if (b < 55){
      int qb, pb;
      decode_blk(b, qb, pb);
      bool zero = (qb == pb) && (qi > pi);
      if (!zero){
        int q = qb*4 + qi, p = pb*4 + pi;
        int fa = (q * 40 + p) * 3 + l;
        float ga = gamma[fa], ba = beta[fa];
        float wm[4] = {0,0,0,0};
        #pragma unroll
        for (int a = 0; a < 4; a++){
          float wa = W1[(size_t)a * FF * 512 + (size_t)fa * 512 + n0 + ni];
          #pragma unroll
          for (int s = 0; s < 4; s++) wm[s] += u[a][s] * wa;
        }
        #pragma unroll
        for (int s = 0; s < 4; s++){ tg[s] = ga * wm[s]; tb[s] = ba * wm[s]; }
        if (p != q){
          int fb = (p * 40 + q) * 3 + l;
          float gb = gamma[fb], bb = beta[fb];
          float wn[4] = {0,0,0,0};
          #pragma unroll
          for (int a = 0; a < 4; a++){
            float wb = W1[(size_t)a * FF * 512 + (size_t)fb * 512 + n0 + ni];
            #pragma unroll
            for (int s = 0; s < 4; s++) wn[s] += u[a][s] * wb;
          }
          #pragma unroll
          for (int s = 0; s < 4; s++){ tg[s] += gb * wn[s]; tb[s] += bb * wn[s]; }
        }
      }
    }
    #pragma unroll
    for (int s = 0; s < 4; s++){
      og[s][fi][ni] = f2bf(tg[s]);
      gs[s] += tg[s];
      bs[s] += tb[s];
    }
  }
  #pragma unroll
  for (int s = 0; s < 4; s++){
    atomic_add_f(&gW[s * 512 + n0 + ni], gs[s]);
    atomic_add_f(&bW[s * 512 + n0 + ni], bs[s]);
  }
  __syncthreads();
  for (int it = 0; it < 8; it++){
    int idx = it * 256 + tid;      // 2048 u16x8 chunks: [s][nn][c]
    int c = idx & 7;
    int rrow = idx >> 3;
    int s = rrow >> 6, nn = rrow & 63;
    unsigned short o[8];
    #pragma unroll
    for (int j = 0; j < 8; j++) o[j] = og[s][c*8 + j][nn];
    *reinterpret_cast<u16x8*>(&Wg[((size_t)s * 512 + n0 + nn) * FR + f0 + c * 8]) = *(const u16x8*)o;
  }
}

__global__ __launch_bounds__(256) void k_w2t(
    const float* __restrict__ W2, const float* __restrict__ U,
    unsigned short* __restrict__ W2t)
{
  __shared__ float t[64][65];
  int n0 = blockIdx.x * 64, k0 = blockIdx.y * 64, s = blockIdx.z;
  float u0 = U[s], u1 = U[4+s], u2 = U[8+s], u3 = U[12+s];
  int tid = threadIdx.x;
  #pragma unroll 4
  for (int rep = 0; rep < 16; rep++){
    int idx = rep * 256 + tid;
    int ki = idx >> 6, ni = idx & 63;
    size_t base = (size_t)(k0 + ki) * 512 + (n0 + ni);
    t[ki][ni] = u0*W2[base] + u1*W2[base + 512*512]
              + u2*W2[base + 2*512*512] + u3*W2[base + 3*512*512];
  }
  __syncthreads();
  #pragma unroll 4
  for (int rep = 0; rep < 16; rep++){
    int idx = rep * 256 + tid;
    int ni = idx >> 6, ki = idx & 63;
    W2t[((size_t)s * 512 + n0 + ni) * 512 + k0 + ki] = f2bf(t[ki][ni]);
  }
}

__global__ void k_w3(const float* __restrict__ W3, const float* __restrict__ U,
                     float* __restrict__ W3s)
{
  int idx = blockIdx.x * 256 + threadIdx.x;
  if (idx < 4 * 512){
    int s = idx >> 9, k = idx & 511;
    W3s[idx] = U[s]*W3[k] + U[4+s]*W3[512+k] + U[8+s]*W3[2*512+k] + U[12+s]*W3[3*512+k];
  }
}

// ---------------- GEMM template (128x128 tile, BK=64, bf16 MFMA) ----------------
template<int EPI, int NSPLIT>
__global__ __launch_bounds__(256) void k_gemm(
    const unsigned short* __restrict__ Ag, int lda, int K,
    const unsigned short* __restrict__ Btg,
    const int* __restrict__ list, const int* __restrict__ offs, const int* __restrict__ cnt,
    unsigned short* __restrict__ pout,
    const float* __restrict__ W3s, float* __restrict__ pacc)
{
  __shared__ alignas(16) char smem[32768];
  const int NV = 4 * NSPLIT;
  int b = blockIdx.x;
  int y = (b & 7) + 8 * (b / (8 * NV));
  int v = (b >> 3) % NV;
  int x = v & 3, kh = v >> 2;

  int s = 0, t = y;
  for (; s < 4; s++){
    int nts = (cnt[s] + 127) >> 7;
    if (t < nts) break;
    t -= nts;
  }
  if (s >= 4) return;
  int cntS = cnt[s], offS = offs[s];
  int rt = t, n0 = x * 128;
  int tid = threadIdx.x, w = tid >> 6, lane = tid & 63;
  int wr = w >> 1, wc = w & 1;

  const unsigned short* Bts = Btg + (size_t)s * 512 * K;
  const unsigned short* gA[4];
  const unsigned short* gB[4];
  char* lA[4];
  char* lB[4];
  #pragma unroll
  for (int it = 0; it < 4; it++){
    int g = it * 4 + w;
    int idx = g * 64 + lane;
    int row = idx >> 3, ch = idx & 7;
    int cg = ch ^ (row & 7);
    int gr = rt * 128 + row; gr = gr < cntS ? gr : cntS - 1;
    int atom = list[offS + gr];
    gA[it] = Ag + (size_t)atom * lda + cg * 8;
    lA[it] = smem + g * 1024;
    gB[it] = Bts + (size_t)(n0 + row) * K + cg * 8;
    lB[it] = smem + 16384 + g * 1024;
  }

  int hi = lane >> 4, lo = lane & 15;
  f32x4 acc[4][4];
  #pragma unroll
  for (int mi = 0; mi < 4; mi++)
    #pragma unroll
    for (int ni = 0; ni < 4; ni++)
      #pragma unroll
      for (int r = 0; r < 4; r++) acc[mi][ni][r] = 0.f;

  int abase[4], a7[4], bbase[4], b7[4];
  #pragma unroll
  for (int mi = 0; mi < 4; mi++){ int row = wr*64 + mi*16 + lo; abase[mi] = row*128; a7[mi] = row & 7; }
  #pragma unroll
  for (int ni = 0; ni < 4; ni++){ int row = wc*64 + ni*16 + lo; bbase[ni] = 16384 + row*128; b7[ni] = row & 7; }

  int nk = K / 64;
  int k0 = ((nk * kh) / NSPLIT) * 64;
  int k1 = ((nk * (kh + 1)) / NSPLIT) * 64;

  for (int kt = k0; kt < k1; kt += 64){
    #pragma unroll
    for (int it = 0; it < 4; it++) gload16(gA[it] + kt, lA[it]);
    #pragma unroll
    for (int it = 0; it < 4; it++) gload16(gB[it] + kt, lB[it]);
    __syncthreads();
    #pragma unroll
    for (int kk = 0; kk < 2; kk++){
      bf16x8 af[4], bfr[4];
      #pragma unroll
      for (int mi = 0; mi < 4; mi++)
        af[mi] = *(const bf16x8*)(smem + abase[mi] + (((kk*4 + hi) ^ a7[mi]) << 4));
      #pragma unroll
      for (int ni = 0; ni < 4; ni++)
        bfr[ni] = *(const bf16x8*)(smem + bbase[ni] + (((kk*4 + hi) ^ b7[ni]) << 4));
      #pragma unroll
      for (int mi = 0; mi < 4; mi++)
        #pragma unroll
        for (int ni = 0; ni < 4; ni++)
          acc[mi][ni] = __builtin_amdgcn_mfma_f32_16x16x32_bf16(af[mi], bfr[ni], acc[mi][ni], 0, 0, 0);
    }
    __syncthreads();
  }

  int gn[4];
  #pragma unroll
  for (int ni = 0; ni < 4; ni++) gn[ni] = n0 + wc*64 + ni*16 + lo;

  if (EPI == 0){
    #pragma unroll
    for (int mi = 0; mi < 4; mi++){
      #pragma unroll
      for (int j = 0; j < 4; j++){
        int gr = rt*128 + wr*64 + mi*16 + hi*4 + j;
        if (gr < cntS){
          int atom = list[offS + gr];
          #pragma unroll
          for (int ni = 0; ni < 4; ni++)
            pout[((size_t)kh * NA + atom) * 512 + gn[ni]] = f2bf(acc[mi][ni][j]);
        }
      }
    }
  } else {
    float w3v[4];
    #pragma unroll
    for (int ni = 0; ni < 4; ni++) w3v[ni] = W3s[s * 512 + gn[ni]];
    float* pslot = pacc + (size_t)(x * 2 + wc) * NA;
    #pragma unroll
    for (int mi = 0; mi < 4; mi++){
      #pragma unroll
      for (int j = 0; j < 4; j++){
        int gr = rt*128 + wr*64 + mi*16 + hi*4 + j;
        if (gr < cntS){
          int atom = list[offS + gr];
          float pdot = 0.f;
          #pragma unroll
          for (int ni = 0; ni < 4; ni++)
            pdot += silu(acc[mi][ni][j]) * w3v[ni];
          pdot += __shfl_xor(pdot, 1, 16);
          pdot += __shfl_xor(pdot, 2, 16);
          pdot += __shfl_xor(pdot, 4, 16);
          pdot += __shfl_xor(pdot, 8, 16);
          if (lo == 0) pslot[atom] = pdot;
        }
      }
    }
  }
}

// ---------------- epilogue: combine 4 split-K partials + LN-affine + silu -> h1 -------
__global__ __launch_bounds__(256) void k_epi(
    const unsigned short* __restrict__ pbuf, const float* __restrict__ stats,
    const float* __restrict__ gW, const float* __restrict__ bW,
    const int* __restrict__ numbers, unsigned short* __restrict__ h1)
{
  int w = threadIdx.x >> 6, lane = threadIdx.x & 63;
  int atom = blockIdx.x * 4 + w;
  int s = numbers[atom];
  float mean = stats[2*atom], rstd = stats[2*atom+1];
  int c0 = lane * 8;
  u16x8 a0 = *reinterpret_cast<const u16x8*>(pbuf + (size_t)atom * 512 + c0);
  u16x8 a1 = *reinterpret_cast<const u16x8*>(pbuf + (size_t)(NA + atom) * 512 + c0);
  u16x8 a2 = *reinterpret_cast<const u16x8*>(pbuf + (size_t)(2*NA + atom) * 512 + c0);
  u16x8 a3 = *reinterpret_cast<const u16x8*>(pbuf + (size_t)(3*NA + atom) * 512 + c0);
  unsigned short o[8];
  #pragma unroll
  for (int j = 0; j < 8; j++){
    int c = c0 + j;
    float acc = (bf2f(a0[j]) + bf2f(a1[j])) + (bf2f(a2[j]) + bf2f(a3[j]));
    float vv = rstd * acc + bW[s*512 + c] - mean * rstd * gW[s*512 + c];
    o[j] = f2bf(silu(vv));
  }
  *reinterpret_cast<u16x8*>(h1 + (size_t)atom * 512 + c0) = *(const u16x8*)o;
}

// ---------------- final: sum 8 pacc partials/atom, wave-uniform molecule atomic -------
__global__ __launch_bounds__(256) void k_final2(
    const float* __restrict__ pacc, const int* __restrict__ numbers,
    const int* __restrict__ batch, const float* __restrict__ Wc,
    float* __restrict__ molOut)
{
  int atom = blockIdx.x * 256 + threadIdx.x;
  int lane = threadIdx.x & 63;
  float sum = 0.f;
  #pragma unroll
  for (int p = 0; p < 8; p++) sum += pacc[(size_t)p * NA + atom];
  float val = sum * (1.f / 128.f) + Wc[numbers[atom]];
  int mol = batch[atom];
  int m0 = __shfl(mol, 0, 64);
  int m63 = __shfl(mol, 63, 64);
  if (m0 == m63){
    #pragma unroll
    for (int m = 32; m; m >>= 1) val += __shfl_xor(val, m, 64);
    if (lane == 0) atomic_add_f(&molOut[mol], val);
  } else {
    atomic_add_f(&molOut[mol], val);
  }
}

extern "C" void kernel_launch(void* const* d_in, const int* in_sizes, int n_in,
                              void* d_out, int out_size, void* d_ws, size_t ws_size,
                              hipStream_t stream)
{
  const float* pos     = (const float*)d_in[0];
  const float* cells   = (const float*)d_in[1];
  const int*   numbers = (const int*)d_in[2];
  const int*   ei      = (const int*)d_in[3];
  const float* eoff    = (const float*)d_in[4];
  const int*   batch   = (const int*)d_in[5];
  const float* U       = (const float*)d_in[6];
  const float* gamma   = (const float*)d_in[7];
  const float* beta    = (const float*)d_in[8];
  const float* W1      = (const float*)d_in[9];
  const float* W2      = (const float*)d_in[10];
  const float* W3      = (const float*)d_in[11];
  const float* Wc      = (const float*)d_in[12];
  float* out = (float*)d_out;

  char* ws = (char*)d_ws;
  size_t off = 0;
  auto alloc = [&](size_t bytes) -> void* {
    void* p = ws + off;
    off += (bytes + 255) & ~(size_t)255;
    return p;
  };
  unsigned short* ps   = (unsigned short*)alloc((size_t)NA * FR * 2);      // 88 MB
  unsigned short* pbuf = (unsigned short*)alloc((size_t)4 * NA * 512 * 2); // 64 MB
  float* stats         = (float*)alloc((size_t)NA * 2 * 4);
  unsigned short* Wg1  = (unsigned short*)alloc((size_t)4 * 512 * FR * 2); // 11 MB
  unsigned short* W2t  = (unsigned short*)alloc((size_t)4 * 512 * 512 * 2);
  float* W3s           = (float*)alloc(4 * 512 * 4);
  unsigned short* h1   = (unsigned short*)alloc((size_t)NA * 512 * 2);
  float* pacc          = (float*)alloc((size_t)8 * NA * 4);
  int* list            = (int*)alloc(NA * 4);
  int* perm            = (int*)alloc((size_t)NE * 4);
  int* startsK         = (int*)alloc((65536 + 1) * 4);
  // contiguous zero-init region: cnt64k + gW + bW (one memset)
  int* cnt64k          = (int*)alloc(65536 * 4);
  float* gW            = (float*)alloc(4 * 512 * 4);
  float* bW            = (float*)alloc(4 * 512 * 4);
  int* cursor64k       = (int*)alloc(65536 * 4);
  int* bsum            = (int*)alloc(256 * 4);
  int* boff            = (int*)alloc(256 * 4);
  int* bhist           = (int*)alloc(64 * 4 * 4);
  int* boffs           = (int*)alloc(64 * 4 * 4);
  int* ints            = (int*)alloc(64);
  int* cnt = ints; int* offs = ints + 8;

  hipMemsetAsync(cnt64k, 0, 65536 * 4 + 2 * 4 * 512 * 4, stream);
  hipMemsetAsync(out, 0, (size_t)out_size * 4, stream);

  // edge counting sort by (recv, sender-species)
  k_hist<<<NE / 256, 256, 0, stream>>>(ei, numbers, cnt64k);
  k_scanA<<<256, 256, 0, stream>>>(cnt64k, bsum);
  k_scanB<<<1, 256, 0, stream>>>(bsum, boff, startsK);
  k_scanC<<<256, 256, 0, stream>>>(cnt64k, boff, startsK, cursor64k);
  k_sortperm<<<NE / 256, 256, 0, stream>>>(ei, numbers, cursor64k, perm);

  // atom species grouping: contention-free stable counting sort
  k_acount<<<NA / 256, 256, 0, stream>>>(numbers, bhist);
  k_aoffs<<<1, 64, 0, stream>>>(bhist, boffs, ints);
  k_aplace<<<NA / 256, 256, 0, stream>>>(numbers, boffs, list);

  // fused edge-accumulate + U-mix + 6-wave-split folded ps + LN stats
  k_atom<<<NA, 384, 0, stream>>>(pos, cells, ei, eoff, batch, startsK, perm, U, ps, stats);

  // weight prep (single pass over W1; W2 mix; W3 mix)
  k_wg3<<<dim3(8, 42), 256, 0, stream>>>(W1, U, gamma, beta, Wg1, gW, bW);
  k_w2t<<<dim3(8, 8, 4), 256, 0, stream>>>(W2, U, W2t);
  k_w3<<<8, 256, 0, stream>>>(W3, U, W3s);

  // GEMM1 split-K=4 (K=2688, 2176 blocks), then LN+silu epilogue
  k_gemm<0, 4><<<2176, 256, 0, stream>>>(ps, FR, FR, Wg1, list, offs, cnt,
                                         pbuf, nullptr, nullptr);
  k_epi<<<NA / 4, 256, 0, stream>>>(pbuf, stats, gW, bW, numbers, h1);

  // GEMM2 with fused silu + W3 dot -> per-atom partials (atomic-free)
  k_gemm<2, 1><<<544, 256, 0, stream>>>(h1, 512, 512, W2t, list, offs, cnt,
                                        nullptr, W3s, pacc);
  k_final2<<<NA / 256, 256, 0, stream>>>(pacc, numbers, batch, Wc, out);
}

// Round 16
// 314.565 us; speedup vs baseline: 1.1524x; 1.0141x over previous
//
#include <hip/hip_runtime.h>

#define NA   16384
#define NE   524288
#define NM   256
#define FF   4800
#define FR   2688   // folded K: 55 pair-blocks * 48 + 48 pad ; f' = b*48 + l*16 + qi*4 + pi
#define HH   512
#define NMX  10
#define NSPH 9

typedef __bf16 bf16x8 __attribute__((ext_vector_type(8)));
typedef float  f32x4  __attribute__((ext_vector_type(4)));
typedef unsigned short u16x8 __attribute__((ext_vector_type(8)));

__constant__ int g_ka[22] = {0, 1,1,1,2,2,3, 4,4,4,4,4, 5,5,5,5, 6,6,6, 7,7, 8};
__constant__ int g_kb[22] = {0, 1,2,3,2,3,3, 4,5,6,7,8, 5,6,7,8, 6,7,8, 7,8, 8};

__device__ inline unsigned short f2bf(float x){
  return __builtin_bit_cast(unsigned short, (__bf16)x);
}
__device__ inline float bf2f(unsigned short h){
  unsigned int u = ((unsigned int)h) << 16;
  return __builtin_bit_cast(float, u);
}
__device__ inline void atomic_add_f(float* p, float v){
  __hip_atomic_fetch_add(p, v, __ATOMIC_RELAXED, __HIP_MEMORY_SCOPE_AGENT);
}
__device__ inline void gload16(const void* g, void* l){
  __builtin_amdgcn_global_load_lds(
      (const __attribute__((address_space(1))) unsigned int*)g,
      (__attribute__((address_space(3))) unsigned int*)l, 16, 0, 0);
}
__device__ inline float silu(float x){ return x / (1.f + __expf(-x)); }

// decode pair-block b (0..54) -> (qb, pb), qb <= pb < 10
__device__ inline void decode_blk(int b, int& qb, int& pb){
  int q = 0, rem = b;
  while (rem >= 10 - q){ rem -= 10 - q; q++; }
  qb = q; pb = q + rem;
}

// full 4x4 pair block for one l (CNT components), outputs only
template<int CNT>
__device__ inline void ps_block(const float* __restrict__ cl, int qb, int pb, int off,
                                float nrm, bool diag, unsigned short* ob){
  float cq[4][CNT], cp[4][CNT];
  #pragma unroll
  for (int i = 0; i < 4; i++)
    #pragma unroll
    for (int k = 0; k < CNT; k++){
      cq[i][k] = cl[(qb*4 + i)*9 + off + k];
      cp[i][k] = cl[(pb*4 + i)*9 + off + k];
    }
  #pragma unroll
  for (int qi = 0; qi < 4; qi++)
    #pragma unroll
    for (int pi = 0; pi < 4; pi++){
      float v = 0.f;
      #pragma unroll
      for (int k = 0; k < CNT; k++) v += cq[qi][k] * cp[pi][k];
      v *= nrm;
      if (diag && qi > pi) v = 0.f;
      ob[qi*4 + pi] = f2bf(v);
    }
}

// half (2 qi rows x 4 pi) of a 4x4 pair block: 8 outputs, outputs only
template<int CNT>
__device__ inline void ps_block_half(const float* __restrict__ cl, int qb, int pb, int off,
                                     float nrm, bool diag, int qh, unsigned short* ob){
  float cq[2][CNT], cp[4][CNT];
  #pragma unroll
  for (int i = 0; i < 2; i++)
    #pragma unroll
    for (int k = 0; k < CNT; k++)
      cq[i][k] = cl[(qb*4 + qh*2 + i)*9 + off + k];
  #pragma unroll
  for (int i = 0; i < 4; i++)
    #pragma unroll
    for (int k = 0; k < CNT; k++)
      cp[i][k] = cl[(pb*4 + i)*9 + off + k];
  #pragma unroll
  for (int qi = 0; qi < 2; qi++)
    #pragma unroll
    for (int pi = 0; pi < 4; pi++){
      int qg = qh*2 + qi;
      float v = 0.f;
      #pragma unroll
      for (int k = 0; k < CNT; k++) v += cq[qi][k] * cp[pi][k];
      v *= nrm;
      if (diag && qg > pi) v = 0.f;
      ob[qi*4 + pi] = f2bf(v);
    }
}

__device__ inline int block_scan_excl(int v, int tid, int* lds){
  int lane = tid & 63, w = tid >> 6;
  int x = v;
  #pragma unroll
  for (int d = 1; d < 64; d <<= 1){
    int y = __shfl_up(x, d, 64);
    if (lane >= d) x += y;
  }
  if (lane == 63) lds[w] = x;
  __syncthreads();
  int wsum = 0;
  for (int i = 0; i < w; i++) wsum += lds[i];
  return wsum + x - v;
}

// ---------------- edge hist (2048 blocks) + atom hist (64 blocks), fused --------------
__global__ __launch_bounds__(256) void k_hist(const int* __restrict__ ei,
                                              const int* __restrict__ numbers,
                                              int* __restrict__ cnt64k,
                                              int* __restrict__ bhist){
  __shared__ int h[4];
  int blk = blockIdx.x, tid = threadIdx.x;
  if (blk < 2048){
    int e = blk * 256 + tid;
    int key = ei[NE + e] * 4 + numbers[ei[e]];
    atomicAdd(&cnt64k[key], 1);
  } else {
    if (tid < 4) h[tid] = 0;
    __syncthreads();
    atomicAdd(&h[numbers[(blk - 2048) * 256 + tid]], 1);
    __syncthreads();
    if (tid < 4) bhist[(blk - 2048) * 4 + tid] = h[tid];
  }
}

__global__ __launch_bounds__(256) void k_scanA(const int* __restrict__ cnt64k,
                                               int* __restrict__ bsum){
  __shared__ int lds[4];
  int tid = threadIdx.x;
  int v = cnt64k[blockIdx.x * 256 + tid];
  int lane = tid & 63;
  #pragma unroll
  for (int m = 32; m; m >>= 1) v += __shfl_xor(v, m, 64);
  if (lane == 0) lds[tid >> 6] = v;
  __syncthreads();
  if (tid == 0) bsum[blockIdx.x] = lds[0] + lds[1] + lds[2] + lds[3];
}

// scan of 256 block sums + atom-species offsets (fused serial tail)
__global__ __launch_bounds__(256) void k_scanB(const int* __restrict__ bsum,
                                               int* __restrict__ boff, int* __restrict__ starts,
                                               const int* __restrict__ bhist,
                                               int* __restrict__ boffs, int* __restrict__ ints){
  __shared__ int lds[4];
  int tid = threadIdx.x;
  int v = bsum[tid];
  int e = block_scan_excl(v, tid, lds);
  boff[tid] = e;
  if (tid == 0){
    starts[65536] = NE;
    int* cnt = ints; int* offs = ints + 8;
    int tot[4] = {0,0,0,0};
    for (int b = 0; b < 64; b++)
      for (int s = 0; s < 4; s++) tot[s] += bhist[b*4 + s];
    int o = 0;
    for (int s = 0; s < 4; s++){ cnt[s] = tot[s]; offs[s] = o; o += tot[s]; }
    offs[4] = o;
    int run[4];
    for (int s = 0; s < 4; s++) run[s] = offs[s];
    for (int b = 0; b < 64; b++)
      for (int s = 0; s < 4; s++){ boffs[b*4 + s] = run[s]; run[s] += bhist[b*4 + s]; }
  }
}

__global__ __launch_bounds__(256) void k_scanC(const int* __restrict__ cnt64k,
                                               const int* __restrict__ boff,
                                               int* __restrict__ starts, int* __restrict__ cursor){
  __shared__ int lds[4];
  int tid = threadIdx.x;
  int bin = blockIdx.x * 256 + tid;
  int v = cnt64k[bin];
  int e = block_scan_excl(v, tid, lds) + boff[blockIdx.x];
  starts[bin] = e;
  cursor[bin] = e;
}

__global__ __launch_bounds__(256) void k_sortperm(const int* __restrict__ ei,
                                                  const int* __restrict__ numbers,
                                                  int* __restrict__ cursor, int* __restrict__ perm){
  int e = blockIdx.x * 256 + threadIdx.x;
  if (e < NE){
    int key = ei[NE + e] * 4 + numbers[ei[e]];
    int p = atomicAdd(&cursor[key], 1);
    perm[p] = e;
  }
}

__global__ __launch_bounds__(256) void k_aplace(const int* __restrict__ numbers,
                                                const int* __restrict__ boffs,
                                                int* __restrict__ list){
  __shared__ int ws[4][4];
  int tid = threadIdx.x, w = tid >> 6, lane = tid & 63;
  int i = blockIdx.x * 256 + tid;
  int sp = numbers[i];
  int rank = 0;
  #pragma unroll
  for (int s = 0; s < 4; s++){
    unsigned long long m = __ballot(sp == s);
    if (s == sp) rank = __popcll(m & (((unsigned long long)1 << lane) - 1));
    if (lane == 0) ws[w][s] = __popcll(m);
  }
  __syncthreads();
  int pre = 0;
  for (int w2 = 0; w2 < w; w2++) pre += ws[w2][sp];
  list[boffs[blockIdx.x * 4 + sp] + pre + rank] = i;
}

// ---------------- fused per-atom: edge accum -> U-mix -> ps (6-wave) + Gram stats -----
__global__ __launch_bounds__(384) void k_atom(
    const float* __restrict__ pos, const float* __restrict__ cells,
    const int* __restrict__ ei, const float* __restrict__ eoff,
    const int* __restrict__ batch, const int* __restrict__ startsK,
    const int* __restrict__ perm, const float* __restrict__ U,
    unsigned short* __restrict__ ps, float* __restrict__ stats)
{
  __shared__ float Rl[64][NMX];
  __shared__ float Yl[64][NSPH];
  __shared__ float csr[360];
  __shared__ float cl[360];
  __shared__ float ul[16];
  int atom = blockIdx.x;
  int tid = threadIdx.x;
  if (tid < 16) ul[tid] = U[tid];
  int e0 = startsK[atom * 4], e1 = startsK[atom * 4 + 4];
  float px = pos[atom*3+0], py = pos[atom*3+1], pz = pos[atom*3+2];
  int sp = tid / 90, n = (tid % 90) / 9, k = tid % 9;
  int aS = 0, aE = 0;
  if (tid < 360){ aS = startsK[atom * 4 + sp]; aE = startsK[atom * 4 + sp + 1]; }
  float acc = 0.f;
  for (int base = e0; base < e1; base += 64){
    int nch = min(64, e1 - base);
    if (tid < nch){
      int e = perm[base + tid];
      int snd = ei[e];
      const float* C = cells + (size_t)batch[snd] * 9;
      float o0 = eoff[e*3+0], o1 = eoff[e*3+1], o2 = eoff[e*3+2];
      float rx = px - pos[snd*3+0] + o0*C[0] + o1*C[3] + o2*C[6];
      float ry = py - pos[snd*3+1] + o0*C[1] + o1*C[4] + o2*C[7];
      float rz = pz - pos[snd*3+2] + o0*C[2] + o1*C[5] + o2*C[8];
      float r = sqrtf(rx*rx + ry*ry + rz*rz + 1e-12f);
      float inv = 1.f / r;
      float hx = rx*inv, hy = ry*inv, hz = rz*inv;
      float fc = (r < 5.f) ? (0.5f * (__cosf(r * 0.6283185307179586f) + 1.f)) : 0.f;
      #pragma unroll
      for (int nn = 0; nn < NMX; nn++){
        float d = r - (5.f/9.f) * (float)nn;
        Rl[tid][nn] = __expf(-2.f * d * d) * fc;
      }
      Yl[tid][0] = 0.28209479177387814f;
      Yl[tid][1] = 0.4886025119029199f * hy;
      Yl[tid][2] = 0.4886025119029199f * hz;
      Yl[tid][3] = 0.4886025119029199f * hx;
      Yl[tid][4] = 1.0925484305920792f * hx * hy;
      Yl[tid][5] = 1.0925484305920792f * hy * hz;
      Yl[tid][6] = 0.31539156525252005f * (3.f * hz * hz - 1.f);
      Yl[tid][7] = 1.0925484305920792f * hx * hz;
      Yl[tid][8] = 0.5462742152960396f * (hx * hx - hy * hy);
    }
    __syncthreads();
    if (tid < 360){
      int lo2 = max(aS, base), hi2 = min(aE, base + nch);
      for (int e = lo2; e < hi2; e++){
        int j = e - base;
        acc += Rl[j][n] * Yl[j][k];
      }
    }
    __syncthreads();
  }
  if (tid < 360) csr[tid] = acc;
  __syncthreads();
  if (tid < 360){
    int a = tid / 90, nk = tid % 90;
    cl[tid] = ul[a*4+0]*csr[nk] + ul[a*4+1]*csr[90+nk]
            + ul[a*4+2]*csr[180+nk] + ul[a*4+3]*csr[270+nk];
  }
  __syncthreads();
  // ps: w0/w1 -> l=2 halves, w2/w3 -> l=1 halves, w4 -> l=0 full, w5 -> pad + Gram stats
  int w6 = tid >> 6, b = tid & 63;
  if (w6 <= 3 && b < 55){
    int l = (w6 < 2) ? 2 : 1;
    int qh = w6 & 1;
    int qb, pb;
    decode_blk(b, qb, pb);
    bool diag = (qb == pb);
    unsigned short ob[8];
    if (l == 2) ps_block_half<5>(cl, qb, pb, 4, 0.4472135954999579f, diag, qh, ob);
    else        ps_block_half<3>(cl, qb, pb, 1, 0.5773502691896258f, diag, qh, ob);
    unsigned short* dst = ps + (size_t)atom * FR + b * 48 + l * 16 + qh * 8;
    *reinterpret_cast<u16x8*>(dst) = *(const u16x8*)ob;
  } else if (w6 == 4 && b < 55){
    int qb, pb;
    decode_blk(b, qb, pb);
    bool diag = (qb == pb);
    unsigned short ob[16];
    ps_block<1>(cl, qb, pb, 0, 1.f, diag, ob);
    unsigned short* dst = ps + (size_t)atom * FR + b * 48;
    *reinterpret_cast<u16x8*>(dst)     = *(const u16x8*)&ob[0];
    *reinterpret_cast<u16x8*>(dst + 8) = *(const u16x8*)&ob[8];
  } else if (w6 == 5){
    if (b < 6){
      unsigned short zb[8] = {0,0,0,0,0,0,0,0};
      *reinterpret_cast<u16x8*>(ps + (size_t)atom * FR + 2640 + b * 8) = *(const u16x8*)zb;
    }
    // LN stats via closed form:
    //   s1 = sum_l nrm_l * sum_{k in l} S[k]^2,  S[k] = sum_q cl[q][k]
    //   s2 = sum_l nrm_l^2 * sum_{k,k' in l} G[k,k']^2,  G = sum_q cl[q][k]*cl[q][k']
    float c1 = 0.f, c2 = 0.f;
    if (b >= 8 && b < 17){
      int kk = b - 8;
      float S = 0.f;
      for (int q = 0; q < 40; q++) S += cl[q*9 + kk];
      float nrm = (kk == 0) ? 1.f : ((kk < 4) ? 0.5773502691896258f : 0.4472135954999579f);
      c1 = nrm * S * S;
    } else if (b >= 24 && b < 46){
      int j = b - 24;
      int ka = g_ka[j], kb = g_kb[j];
      float G = 0.f;
      for (int q = 0; q < 40; q++) G += cl[q*9 + ka] * cl[q*9 + kb];
      float n2 = (ka == 0) ? 1.f : ((ka < 4) ? (1.f/3.f) : 0.2f);
      float mul = (ka == kb) ? 1.f : 2.f;
      c2 = n2 * mul * G * G;
    }
    #pragma unroll
    for (int m = 32; m; m >>= 1){ c1 += __shfl_xor(c1, m, 64); c2 += __shfl_xor(c2, m, 64); }
    if (b == 0){
      float mean = c1 * (1.f / FF);
      float var = c2 * (1.f / FF) - mean * mean;
      var = fmaxf(var, 0.f);
      stats[2*atom]   = mean;
      stats[2*atom+1] = rsqrtf(var + 1e-5f);
    }
  }
}

// ---------------- weight prep v3: SINGLE pass over W1, all 4 species at once ----------
__global__ __launch_bounds__(256) void k_wg3(
    const float* __restrict__ W1, const float* __restrict__ U,
    const float* __restrict__ gamma, const float* __restrict__ beta,
    unsigned short* __restrict__ Wg, float* __restrict__ gW, float* __restrict__ bW)
{
  __shared__ unsigned short og[4][64][64]; // [s][fi][ni], 32 KB
  int n0 = blockIdx.x * 64, f0 = blockIdx.y * 64;
  int tid = threadIdx.x, ni = tid & 63;
  float u[4][4];
  #pragma unroll
  for (int a = 0; a < 4; a++)
    #pragma unroll
    for (int s = 0; s < 4; s++) u[a][s] = U[a*4 + s];
  float gs[4] = {0,0,0,0}, bs[4] = {0,0,0,0};
  for (int rep = 0; rep < 16; rep++){
    int fi = rep * 4 + (tid >> 6);
    int fp = f0 + fi;
    int b = fp / 48, r = fp % 48;
    int l = r >> 4, qi = (r >> 2) & 3, pi = r & 3;
    float tg[4] = {0,0,0,0}, tb[4] = {0,0,0,0};
    if (b < 55){
      int qb, pb;
      decode_blk(b, qb, pb);
      bool zero = (qb == pb) && (qi > pi);
      if (!zero){
        int q = qb*4 + qi, p = pb*4 + pi;
        int fa = (q * 40 + p) * 3 + l;
        float ga = gamma[fa], ba = beta[fa];
        float wm[4] = {0,0,0,0};
        #pragma unroll
        for (int a = 0; a < 4; a++){
          float wa = W1[(size_t)a * FF * 512 + (size_t)fa * 512 + n0 + ni];
          #pragma unroll
          for (int s = 0; s < 4; s++) wm[s] += u[a][s] * wa;
        }
        #pragma unroll
        for (int s = 0; s < 4; s++){ tg[s] = ga * wm[s]; tb[s] = ba * wm[s]; }
        if (p != q){
          int fb = (p * 40 + q) * 3 + l;
          float gb = gamma[fb], bb = beta[fb];
          float wn[4] = {0,0,0,0};
          #pragma unroll
          for (int a = 0; a < 4; a++){
            float wb = W1[(size_t)a * FF * 512 + (size_t)fb * 512 + n0 + ni];
            #pragma unroll
            for (int s = 0; s < 4; s++) wn[s] += u[a][s] * wb;
          }
          #pragma unroll
          for (int s = 0; s < 4; s++){ tg[s] += gb * wn[s]; tb[s] += bb * wn[s]; }
        }
      }
    }
    #pragma unroll
    for (int s = 0; s < 4; s++){
      og[s][fi][ni] = f2bf(tg[s]);
      gs[s] += tg[s];
      bs[s] += tb[s];
    }
  }
  #pragma unroll
  for (int s = 0; s < 4; s++){
    atomic_add_f(&gW[s * 512 + n0 + ni], gs[s]);
    atomic_add_f(&bW[s * 512 + n0 + ni], bs[s]);
  }
  __syncthreads();
  for (int it = 0; it < 8; it++){
    int idx = it * 256 + tid;      // 2048 u16x8 chunks: [s][nn][c]
    int c = idx & 7;
    int rrow = idx >> 3;
    int s = rrow >> 6, nn = rrow & 63;
    unsigned short o[8];
    #pragma unroll
    for (int j = 0; j < 8; j++) o[j] = og[s][c*8 + j][nn];
    *reinterpret_cast<u16x8*>(&Wg[((size_t)s * 512 + n0 + nn) * FR + f0 + c * 8]) = *(const u16x8*)o;
  }
}

__global__ __launch_bounds__(256) void k_w2t(
    const float* __restrict__ W2, const float* __restrict__ U,
    unsigned short* __restrict__ W2t)
{
  __shared__ float t[64][65];
  int n0 = blockIdx.x * 64, k0 = blockIdx.y * 64, s = blockIdx.z;
  float u0 = U[s], u1 = U[4+s], u2 = U[8+s], u3 = U[12+s];
  int tid = threadIdx.x;
  #pragma unroll 4
  for (int rep = 0; rep < 16; rep++){
    int idx = rep * 256 + tid;
    int ki = idx >> 6, ni = idx & 63;
    size_t base = (size_t)(k0 + ki) * 512 + (n0 + ni);
    t[ki][ni] = u0*W2[base] + u1*W2[base + 512*512]
              + u2*W2[base + 2*512*512] + u3*W2[base + 3*512*512];
  }
  __syncthreads();
  #pragma unroll 4
  for (int rep = 0; rep < 16; rep++){
    int idx = rep * 256 + tid;
    int ni = idx >> 6, ki = idx & 63;
    W2t[((size_t)s * 512 + n0 + ni) * 512 + k0 + ki] = f2bf(t[ki][ni]);
  }
}

__global__ void k_w3(const float* __restrict__ W3, const float* __restrict__ U,
                     float* __restrict__ W3s)
{
  int idx = blockIdx.x * 256 + threadIdx.x;
  if (idx < 4 * 512){
    int s = idx >> 9, k = idx & 511;
    W3s[idx] = U[s]*W3[k] + U[4+s]*W3[512+k] + U[8+s]*W3[2*512+k] + U[12+s]*W3[3*512+k];
  }
}

// ---------------- GEMM template (128x128 tile, BK=64, bf16 MFMA) ----------------
template<int EPI, int NSPLIT>
__global__ __launch_bounds__(256) void k_gemm(
    const unsigned short* __restrict__ Ag, int lda, int K,
    const unsigned short* __restrict__ Btg,
    const int* __restrict__ list, const int* __restrict__ offs, const int* __restrict__ cnt,
    unsigned short* __restrict__ pout,
    const float* __restrict__ W3s, float* __restrict__ pacc)
{
  __shared__ alignas(16) char smem[32768];
  const int NV = 4 * NSPLIT;
  int b = blockIdx.x;
  int y = (b & 7) + 8 * (b / (8 * NV));
  int v = (b >> 3) % NV;
  int x = v & 3, kh = v >> 2;

  int s = 0, t = y;
  for (; s < 4; s++){
    int nts = (cnt[s] + 127) >> 7;
    if (t < nts) break;
    t -= nts;
  }
  if (s >= 4) return;
  int cntS = cnt[s], offS = offs[s];
  int rt = t, n0 = x * 128;
  int tid = threadIdx.x, w = tid >> 6, lane = tid & 63;
  int wr = w >> 1, wc = w & 1;

  const unsigned short* Bts = Btg + (size_t)s * 512 * K;
  const unsigned short* gA[4];
  const unsigned short* gB[4];
  char* lA[4];
  char* lB[4];
  #pragma unroll
  for (int it = 0; it < 4; it++){
    int g = it * 4 + w;
    int idx = g * 64 + lane;
    int row = idx >> 3, ch = idx & 7;
    int cg = ch ^ (row & 7);
    int gr = rt * 128 + row; gr = gr < cntS ? gr : cntS - 1;
    int atom = list[offS + gr];
    gA[it] = Ag + (size_t)atom * lda + cg * 8;
    lA[it] = smem + g * 1024;
    gB[it] = Bts + (size_t)(n0 + row) * K + cg * 8;
    lB[it] = smem + 16384 + g * 1024;
  }

  int hi = lane >> 4, lo = lane & 15;
  f32x4 acc[4][4];
  #pragma unroll
  for (int mi = 0; mi < 4; mi++)
    #pragma unroll
    for (int ni = 0; ni < 4; ni++)
      #pragma unroll
      for (int r = 0; r < 4; r++) acc[mi][ni][r] = 0.f;

  int abase[4], a7[4], bbase[4], b7[4];
  #pragma unroll
  for (int mi = 0; mi < 4; mi++){ int row = wr*64 + mi*16 + lo; abase[mi] = row*128; a7[mi] = row & 7; }
  #pragma unroll
  for (int ni = 0; ni < 4; ni++){ int row = wc*64 + ni*16 + lo; bbase[ni] = 16384 + row*128; b7[ni] = row & 7; }

  int nk = K / 64;
  int k0 = ((nk * kh) / NSPLIT) * 64;
  int k1 = ((nk * (kh + 1)) / NSPLIT) * 64;

  for (int kt = k0; kt < k1; kt += 64){
    #pragma unroll
    for (int it = 0; it < 4; it++) gload16(gA[it] + kt, lA[it]);
    #pragma unroll
    for (int it = 0; it < 4; it++) gload16(gB[it] + kt, lB[it]);
    __syncthreads();
    #pragma unroll
    for (int kk = 0; kk < 2; kk++){
      bf16x8 af[4], bfr[4];
      #pragma unroll
      for (int mi = 0; mi < 4; mi++)
        af[mi] = *(const bf16x8*)(smem + abase[mi] + (((kk*4 + hi) ^ a7[mi]) << 4));
      #pragma unroll
      for (int ni = 0; ni < 4; ni++)
        bfr[ni] = *(const bf16x8*)(smem + bbase[ni] + (((kk*4 + hi) ^ b7[ni]) << 4));
      #pragma unroll
      for (int mi = 0; mi < 4; mi++)
        #pragma unroll
        for (int ni = 0; ni < 4; ni++)
          acc[mi][ni] = __builtin_amdgcn_mfma_f32_16x16x32_bf16(af[mi], bfr[ni], acc[mi][ni], 0, 0, 0);
    }
    __syncthreads();
  }

  int gn[4];
  #pragma unroll
  for (int ni = 0; ni < 4; ni++) gn[ni] = n0 + wc*64 + ni*16 + lo;

  if (EPI == 0){
    #pragma unroll
    for (int mi = 0; mi < 4; mi++){
      #pragma unroll
      for (int j = 0; j < 4; j++){
        int gr = rt*128 + wr*64 + mi*16 + hi*4 + j;
        if (gr < cntS){
          int atom = list[offS + gr];
          #pragma unroll
          for (int ni = 0; ni < 4; ni++)
            pout[((size_t)kh * NA + atom) * 512 + gn[ni]] = f2bf(acc[mi][ni][j]);
        }
      }
    }
  } else {
    float w3v[4];
    #pragma unroll
    for (int ni = 0; ni < 4; ni++) w3v[ni] = W3s[s * 512 + gn[ni]];
    float* pslot = pacc + (size_t)(x * 2 + wc) * NA;
    #pragma unroll
    for (int mi = 0; mi < 4; mi++){
      #pragma unroll
      for (int j = 0; j < 4; j++){
        int gr = rt*128 + wr*64 + mi*16 + hi*4 + j;
        if (gr < cntS){
          int atom = list[offS + gr];
          float pdot = 0.f;
          #pragma unroll
          for (int ni = 0; ni < 4; ni++)
            pdot += silu(acc[mi][ni][j]) * w3v[ni];
          pdot += __shfl_xor(pdot, 1, 16);
          pdot += __shfl_xor(pdot, 2, 16);
          pdot += __shfl_xor(pdot, 4, 16);
          pdot += __shfl_xor(pdot, 8, 16);
          if (lo == 0) pslot[atom] = pdot;
        }
      }
    }
  }
}

// ---------------- epilogue: combine 4 split-K partials + LN-affine + silu -> h1 -------
__global__ __launch_bounds__(256) void k_epi(
    const unsigned short* __restrict__ pbuf, const float* __restrict__ stats,
    const float* __restrict__ gW, const float* __restrict__ bW,
    const int* __restrict__ numbers, unsigned short* __restrict__ h1)
{
  int w = threadIdx.x >> 6, lane = threadIdx.x & 63;
  int atom = blockIdx.x * 4 + w;
  int s = numbers[atom];
  float mean = stats[2*atom], rstd = stats[2*atom+1];
  int c0 = lane * 8;
  u16x8 a0 = *reinterpret_cast<const u16x8*>(pbuf + (size_t)atom * 512 + c0);
  u16x8 a1 = *reinterpret_cast<const u16x8*>(pbuf + (size_t)(NA + atom) * 512 + c0);
  u16x8 a2 = *reinterpret_cast<const u16x8*>(pbuf + (size_t)(2*NA + atom) * 512 + c0);
  u16x8 a3 = *reinterpret_cast<const u16x8*>(pbuf + (size_t)(3*NA + atom) * 512 + c0);
  unsigned short o[8];
  #pragma unroll
  for (int j = 0; j < 8; j++){
    int c = c0 + j;
    float acc = (bf2f(a0[j]) + bf2f(a1[j])) + (bf2f(a2[j]) + bf2f(a3[j]));
    float vv = rstd * acc + bW[s*512 + c] - mean * rstd * gW[s*512 + c];
    o[j] = f2bf(silu(vv));
  }
  *reinterpret_cast<u16x8*>(h1 + (size_t)atom * 512 + c0) = *(const u16x8*)o;
}

// ---------------- final: sum 8 pacc partials/atom, wave-uniform molecule atomic -------
__global__ __launch_bounds__(256) void k_final2(
    const float* __restrict__ pacc, const int* __restrict__ numbers,
    const int* __restrict__ batch, const float* __restrict__ Wc,
    float* __restrict__ molOut)
{
  int atom = blockIdx.x * 256 + threadIdx.x;
  int lane = threadIdx.x & 63;
  float sum = 0.f;
  #pragma unroll
  for (int p = 0; p < 8; p++) sum += pacc[(size_t)p * NA + atom];
  float val = sum * (1.f / 128.f) + Wc[numbers[atom]];
  int mol = batch[atom];
  int m0 = __shfl(mol, 0, 64);
  int m63 = __shfl(mol, 63, 64);
  if (m0 == m63){
    #pragma unroll
    for (int m = 32; m; m >>= 1) val += __shfl_xor(val, m, 64);
    if (lane == 0) atomic_add_f(&molOut[mol], val);
  } else {
    atomic_add_f(&molOut[mol], val);
  }
}

extern "C" void kernel_launch(void* const* d_in, const int* in_sizes, int n_in,
                              void* d_out, int out_size, void* d_ws, size_t ws_size,
                              hipStream_t stream)
{
  const float* pos     = (const float*)d_in[0];
  const float* cells   = (const float*)d_in[1];
  const int*   numbers = (const int*)d_in[2];
  const int*   ei      = (const int*)d_in[3];
  const float* eoff    = (const float*)d_in[4];
  const int*   batch   = (const int*)d_in[5];
  const float* U       = (const float*)d_in[6];
  const float* gamma   = (const float*)d_in[7];
  const float* beta    = (const float*)d_in[8];
  const float* W1      = (const float*)d_in[9];
  const float* W2      = (const float*)d_in[10];
  const float* W3      = (const float*)d_in[11];
  const float* Wc      = (const float*)d_in[12];
  float* out = (float*)d_out;

  char* ws = (char*)d_ws;
  size_t off = 0;
  auto alloc = [&](size_t bytes) -> void* {
    void* p = ws + off;
    off += (bytes + 255) & ~(size_t)255;
    return p;
  };
  unsigned short* ps   = (unsigned short*)alloc((size_t)NA * FR * 2);      // 88 MB
  unsigned short* pbuf = (unsigned short*)alloc((size_t)4 * NA * 512 * 2); // 64 MB
  float* stats         = (float*)alloc((size_t)NA * 2 * 4);
  unsigned short* Wg1  = (unsigned short*)alloc((size_t)4 * 512 * FR * 2); // 11 MB
  unsigned short* W2t  = (unsigned short*)alloc((size_t)4 * 512 * 512 * 2);
  float* W3s           = (float*)alloc(4 * 512 * 4);
  unsigned short* h1   = (unsigned short*)alloc((size_t)NA * 512 * 2);
  float* pacc          = (float*)alloc((size_t)8 * NA * 4);
  int* list            = (int*)alloc(NA * 4);
  int* perm            = (int*)alloc((size_t)NE * 4);
  int* startsK         = (int*)alloc((65536 + 1) * 4);
  // contiguous zero-init region: cnt64k + gW + bW (one memset)
  int* cnt64k          = (int*)alloc(65536 * 4);
  float* gW            = (float*)alloc(4 * 512 * 4);
  float* bW            = (float*)alloc(4 * 512 * 4);
  int* cursor64k       = (int*)alloc(65536 * 4);
  int* bsum            = (int*)alloc(256 * 4);
  int* boff            = (int*)alloc(256 * 4);
  int* bhist           = (int*)alloc(64 * 4 * 4);
  int* boffs           = (int*)alloc(64 * 4 * 4);
  int* ints            = (int*)alloc(64);
  int* cnt = ints; int* offs = ints + 8;

  hipMemsetAsync(cnt64k, 0, 65536 * 4 + 2 * 4 * 512 * 4, stream);
  hipMemsetAsync(out, 0, (size_t)out_size * 4, stream);

  // edge hist (by recv*4+species) + atom hist, fused
  k_hist<<<2048 + 64, 256, 0, stream>>>(ei, numbers, cnt64k, bhist);
  k_scanA<<<256, 256, 0, stream>>>(cnt64k, bsum);
  k_scanB<<<1, 256, 0, stream>>>(bsum, boff, startsK, bhist, boffs, ints);
  k_scanC<<<256, 256, 0, stream>>>(cnt64k, boff, startsK, cursor64k);
  k_sortperm<<<NE / 256, 256, 0, stream>>>(ei, numbers, cursor64k, perm);
  k_aplace<<<NA / 256, 256, 0, stream>>>(numbers, boffs, list);

  // fused edge-accumulate + U-mix + 6-wave-split folded ps + Gram-form LN stats
  k_atom<<<NA, 384, 0, stream>>>(pos, cells, ei, eoff, batch, startsK, perm, U, ps, stats);

  // weight prep (single pass over W1; W2 mix; W3 mix)
  k_wg3<<<dim3(8, 42), 256, 0, stream>>>(W1, U, gamma, beta, Wg1, gW, bW);
  k_w2t<<<dim3(8, 8, 4), 256, 0, stream>>>(W2, U, W2t);
  k_w3<<<8, 256, 0, stream>>>(W3, U, W3s);

  // GEMM1 split-K=4 (K=2688, 2176 blocks), then LN+silu epilogue
  k_gemm<0, 4><<<2176, 256, 0, stream>>>(ps, FR, FR, Wg1, list, offs, cnt,
                                         pbuf, nullptr, nullptr);
  k_epi<<<NA / 4, 256, 0, stream>>>(pbuf, stats, gW, bW, numbers, h1);

  // GEMM2 with fused silu + W3 dot -> per-atom partials (atomic-free)
  k_gemm<2, 1><<<544, 256, 0, stream>>>(h1, 512, 512, W2t, list, offs, cnt,
                                        nullptr, W3s, pacc);
  k_final2<<<NA / 256, 256, 0, stream>>>(pacc, numbers, batch, Wc, out);
}